// Round 1
// baseline (366.802 us; speedup 1.0000x reference)
//
#include <hip/hip_runtime.h>
#include <hip/hip_bf16.h>

typedef unsigned int u32;
typedef unsigned long long u64;

// ---------------- packed-weight layout in d_ws (u64 indices) ----------------
// conv1: per channel 3 u64: rows(0,1) rows(2,3) row4, 5-bit rows at bit 0 / bit 32
#define W1PS 0      // 6*3 = 18
#define W1PN 18
// conv2: per (o,r): A word = ch0,1,2 in 16-bit fields (bits 0,16,32), B = ch3,4,5
#define W2AS 36     // 16*5 = 80
#define W2AN 116
#define W2BS 196
#define W2BN 276
// fc1: per row j, 8 u64; word cc: bits 0..24 -> in (2cc)*25+k, bits 32..56 -> (2cc+1)*25+k
#define WF1S 356    // 120*8 = 960
#define WF1N 1316
// fc2: per row j, 2 u64 dense over 120 inputs
#define WF2S 2276   // 84*2 = 168
#define WF2N 2444
// fc3: per row j, 2 u64 dense over 84 inputs
#define WF3S 2612   // 10*2 = 20
#define WF3N 2632
#define WTOT 2652   // u64 words = 21216 bytes

__global__ void pack_w(const float* __restrict__ w1, const float* __restrict__ w2,
                       const float* __restrict__ f1, const float* __restrict__ f2,
                       const float* __restrict__ f3, u64* __restrict__ P) {
    int t = threadIdx.x;
    // conv1
    if (t < 6) {
        int ch = t;
        u32 rs[5], rn[5];
        for (int r = 0; r < 5; r++) {
            u32 s = 0, n = 0;
            for (int c = 0; c < 5; c++) {
                float v = w1[ch * 25 + r * 5 + c];
                if (v < 0.0f) s |= 1u << c;
                if (v != 0.0f) n |= 1u << c;
            }
            rs[r] = s; rn[r] = n;
        }
        P[W1PS + ch * 3 + 0] = (u64)rs[0] | ((u64)rs[1] << 32);
        P[W1PS + ch * 3 + 1] = (u64)rs[2] | ((u64)rs[3] << 32);
        P[W1PS + ch * 3 + 2] = (u64)rs[4];
        P[W1PN + ch * 3 + 0] = (u64)rn[0] | ((u64)rn[1] << 32);
        P[W1PN + ch * 3 + 1] = (u64)rn[2] | ((u64)rn[3] << 32);
        P[W1PN + ch * 3 + 2] = (u64)rn[4];
    }
    // conv2
    if (t < 80) {
        int o = t / 5, r = t % 5;
        u64 as_ = 0, an = 0, bs = 0, bn = 0;
        for (int c = 0; c < 6; c++)
            for (int j = 0; j < 5; j++) {
                float v = w2[((o * 6 + c) * 5 + r) * 5 + j];
                int f = (c < 3) ? c : c - 3;
                u64 bit = 1ull << (16 * f + j);
                if (c < 3) { if (v < 0.0f) as_ |= bit; if (v != 0.0f) an |= bit; }
                else       { if (v < 0.0f) bs  |= bit; if (v != 0.0f) bn |= bit; }
            }
        P[W2AS + t] = as_; P[W2AN + t] = an; P[W2BS + t] = bs; P[W2BN + t] = bn;
    }
    // fc1
    for (int w = t; w < 960; w += 256) {
        int j = w / 8, cc = w % 8;
        u64 s = 0, n = 0;
        for (int half = 0; half < 2; half++) {
            int ch = 2 * cc + half;
            for (int k = 0; k < 25; k++) {
                float v = f1[j * 400 + ch * 25 + k];
                u64 bit = 1ull << (32 * half + k);
                if (v < 0.0f) s |= bit;
                if (v != 0.0f) n |= bit;
            }
        }
        P[WF1S + w] = s; P[WF1N + w] = n;
    }
    // fc2
    if (t < 168) {
        int j = t / 2, h = t % 2;
        u64 s = 0, n = 0;
        for (int b = 0; b < 64; b++) {
            int k = h * 64 + b;
            if (k < 120) {
                float v = f2[j * 120 + k];
                if (v < 0.0f) s |= 1ull << b;
                if (v != 0.0f) n |= 1ull << b;
            }
        }
        P[WF2S + t] = s; P[WF2N + t] = n;
    }
    // fc3
    if (t < 20) {
        int j = t / 2, h = t % 2;
        u64 s = 0, n = 0;
        for (int b = 0; b < 64; b++) {
            int k = h * 64 + b;
            if (k < 84) {
                float v = f3[j * 84 + k];
                if (v < 0.0f) s |= 1ull << b;
                if (v != 0.0f) n |= 1ull << b;
            }
        }
        P[WF3S + t] = s; P[WF3N + t] = n;
    }
}

#define G 4  // images per block

__global__ __launch_bounds__(256) void lenet_main(const float* __restrict__ X,
                                                  const u64* __restrict__ P,
                                                  float* __restrict__ out) {
    __shared__ u64 WL[WTOT];
    __shared__ u32 xs[G][32], xn[G][32];
    __shared__ u64 h1As[G][14], h1An[G][14], h1Bs[G][14], h1Bn[G][14];
    __shared__ u32 h2s[G][16], h2n[G][16];
    __shared__ u64 f1s[G][2], f1n[G][2];
    __shared__ u64 f2s[G][2], f2n[G][2];

    const int tid = threadIdx.x;
    const int img0 = blockIdx.x * G;

    // weights -> LDS
    for (int i = tid; i < WTOT; i += 256) WL[i] = P[i];
    // zero accumulator bitplanes
    for (int i = tid; i < G * 14; i += 256) {
        int im = i / 14, r = i % 14;
        h1As[im][r] = 0; h1An[im][r] = 0; h1Bs[im][r] = 0; h1Bn[im][r] = 0;
    }
    if (tid < G * 16) { int im = tid / 16, c = tid % 16; h2s[im][c] = 0; h2n[im][c] = 0; }
    if (tid < G * 2)  { int im = tid / 2, w = tid % 2; f1s[im][w] = 0; f1n[im][w] = 0; f2s[im][w] = 0; f2n[im][w] = 0; }

    // stage B: load + binarize input, pack rows via ballot (wave64 = 2 rows)
    const float* Xb = X + (size_t)img0 * 1024;
    for (int it = 0; it < 4 * G; it++) {
        int flat = it * 256 + tid;
        float v = Xb[flat];
        u64 b_s = __ballot(v < 0.0f);
        u64 b_n = __ballot(v != 0.0f);
        int lane = tid & 63;
        int img = flat >> 10;
        int row = (flat >> 5) & 31;
        if (lane == 0)       { xs[img][row] = (u32)b_s;         xn[img][row] = (u32)b_n; }
        else if (lane == 32) { xs[img][row] = (u32)(b_s >> 32); xn[img][row] = (u32)(b_n >> 32); }
    }
    __syncthreads();

    // stage C: conv1 5x5 + maxpool 2x2 -> h1 [6][14][14], sign/nz bitplanes
    {
        const u64 M2 = 0x0000001F0000001Full;
        for (int idx = tid; idx < G * 1176; idx += 256) {
            int img = idx / 1176, rem = idx % 1176;
            int ch = rem / 196, p = rem % 196, py = p / 14, px = p % 14;
            int oy = 2 * py, sh = 2 * px;
            u32 rs[6], rn[6];
            for (int k = 0; k < 6; k++) { rs[k] = xs[img][oy + k]; rn[k] = xn[img][oy + k]; }
            u64 w0s = WL[W1PS + ch * 3], w1s_ = WL[W1PS + ch * 3 + 1], w4s = WL[W1PS + ch * 3 + 2];
            u64 w0n = WL[W1PN + ch * 3], w1n_ = WL[W1PN + ch * 3 + 1], w4n = WL[W1PN + ch * 3 + 2];
            int best = -1000;
            for (int dy = 0; dy < 2; dy++) {
                u64 p0s = (u64)rs[dy] | ((u64)rs[dy + 1] << 32);
                u64 p0n = (u64)rn[dy] | ((u64)rn[dy + 1] << 32);
                u64 p1s = (u64)rs[dy + 2] | ((u64)rs[dy + 3] << 32);
                u64 p1n = (u64)rn[dy + 2] | ((u64)rn[dy + 3] << 32);
                u32 q4s = rs[dy + 4], q4n = rn[dy + 4];
                for (int dx = 0; dx < 2; dx++) {
                    int t2 = sh + dx;
                    u64 m0 = ((p0n >> t2) & M2) & w0n, x0 = (p0s >> t2) ^ w0s;
                    u64 m1 = ((p1n >> t2) & M2) & w1n_, x1 = (p1s >> t2) ^ w1s_;
                    u32 m4 = ((q4n >> t2) & 31u) & (u32)w4n;
                    u32 x4 = (q4s >> t2) ^ (u32)w4s;
                    int acc = __popcll(m0) + __popcll(m1) + __popc(m4)
                            - 2 * (__popcll(m0 & x0) + __popcll(m1 & x1) + __popc(m4 & x4));
                    best = max(best, acc);
                }
            }
            u64 bit = 1ull << (16 * (ch % 3) + px);
            if (ch < 3) {
                if (best < 0)  atomicOr(&h1As[img][py], bit);
                if (best != 0) atomicOr(&h1An[img][py], bit);
            } else {
                if (best < 0)  atomicOr(&h1Bs[img][py], bit);
                if (best != 0) atomicOr(&h1Bn[img][py], bit);
            }
        }
    }
    __syncthreads();

    // stage D: conv2 5x5x6 + maxpool -> h2 [16][5][5]
    {
        const u64 M3 = 0x0000001F001F001Full;
        for (int idx = tid; idx < G * 400; idx += 256) {
            int img = idx / 400, rem = idx % 400;
            int ch = rem / 25, p = rem % 25, py = p / 5, px = p % 5;
            int oy = 2 * py, sh = 2 * px;
            u64 aS[6], aN[6], bS[6], bN[6];
            for (int k = 0; k < 6; k++) {
                aS[k] = h1As[img][oy + k]; aN[k] = h1An[img][oy + k];
                bS[k] = h1Bs[img][oy + k]; bN[k] = h1Bn[img][oy + k];
            }
            u64 WAS[5], WAN[5], WBS[5], WBN[5];
            for (int r = 0; r < 5; r++) {
                WAS[r] = WL[W2AS + ch * 5 + r]; WAN[r] = WL[W2AN + ch * 5 + r];
                WBS[r] = WL[W2BS + ch * 5 + r]; WBN[r] = WL[W2BN + ch * 5 + r];
            }
            int best = -1000;
            for (int dy = 0; dy < 2; dy++)
                for (int dx = 0; dx < 2; dx++) {
                    int t2 = sh + dx;
                    int acc = 0;
                    for (int r = 0; r < 5; r++) {
                        u64 ma = ((aN[dy + r] >> t2) & M3) & WAN[r];
                        u64 xa = (aS[dy + r] >> t2) ^ WAS[r];
                        acc += __popcll(ma) - 2 * __popcll(ma & xa);
                        u64 mb = ((bN[dy + r] >> t2) & M3) & WBN[r];
                        u64 xb = (bS[dy + r] >> t2) ^ WBS[r];
                        acc += __popcll(mb) - 2 * __popcll(mb & xb);
                    }
                    best = max(best, acc);
                }
            int bit = py * 5 + px;
            if (best < 0)  atomicOr(&h2s[img][ch], 1u << bit);
            if (best != 0) atomicOr(&h2n[img][ch], 1u << bit);
        }
    }
    __syncthreads();

    // stage E: FC1 400 -> 120
    for (int idx = tid; idx < G * 120; idx += 256) {
        int img = idx / 120, j = idx % 120;
        int acc = 0;
        for (int cc = 0; cc < 8; cc++) {
            u64 as_ = (u64)h2s[img][2 * cc] | ((u64)h2s[img][2 * cc + 1] << 32);
            u64 an_ = (u64)h2n[img][2 * cc] | ((u64)h2n[img][2 * cc + 1] << 32);
            u64 m = an_ & WL[WF1N + j * 8 + cc];
            u64 x = as_ ^ WL[WF1S + j * 8 + cc];
            acc += __popcll(m) - 2 * __popcll(m & x);
        }
        if (acc < 0)  atomicOr(&f1s[img][j >> 6], 1ull << (j & 63));
        if (acc != 0) atomicOr(&f1n[img][j >> 6], 1ull << (j & 63));
    }
    __syncthreads();

    // stage F: FC2 120 -> 84
    for (int idx = tid; idx < G * 84; idx += 256) {
        int img = idx / 84, j = idx % 84;
        int acc = 0;
        for (int w = 0; w < 2; w++) {
            u64 m = f1n[img][w] & WL[WF2N + j * 2 + w];
            u64 x = f1s[img][w] ^ WL[WF2S + j * 2 + w];
            acc += __popcll(m) - 2 * __popcll(m & x);
        }
        if (acc < 0)  atomicOr(&f2s[img][j >> 6], 1ull << (j & 63));
        if (acc != 0) atomicOr(&f2n[img][j >> 6], 1ull << (j & 63));
    }
    __syncthreads();

    // stage G: FC3 84 -> 10, write fp32 output
    for (int idx = tid; idx < G * 10; idx += 256) {
        int img = idx / 10, j = idx % 10;
        int acc = 0;
        for (int w = 0; w < 2; w++) {
            u64 m = f2n[img][w] & WL[WF3N + j * 2 + w];
            u64 x = f2s[img][w] ^ WL[WF3S + j * 2 + w];
            acc += __popcll(m) - 2 * __popcll(m & x);
        }
        out[(size_t)(img0 + img) * 10 + j] = (float)acc;
    }
}

extern "C" void kernel_launch(void* const* d_in, const int* in_sizes, int n_in,
                              void* d_out, int out_size, void* d_ws, size_t ws_size,
                              hipStream_t stream) {
    const float* x    = (const float*)d_in[0];
    const float* w1   = (const float*)d_in[1];
    const float* w2   = (const float*)d_in[2];
    const float* wfc1 = (const float*)d_in[3];
    const float* wfc2 = (const float*)d_in[4];
    const float* wfc3 = (const float*)d_in[5];
    float* out = (float*)d_out;
    u64* P = (u64*)d_ws;

    int B = in_sizes[0] / 1024;  // 16384

    pack_w<<<1, 256, 0, stream>>>(w1, w2, wfc1, wfc2, wfc3, P);
    lenet_main<<<B / G, 256, 0, stream>>>(x, P, out);
}

// Round 3
// 214.998 us; speedup vs baseline: 1.7061x; 1.7061x over previous
//
#include <hip/hip_runtime.h>
#include <hip/hip_bf16.h>

typedef unsigned int u32;
typedef unsigned long long u64;

// ---------------- packed-weight layout in d_ws (u64 indices) ----------------
// conv1: 3 ch-pairs (ch 2p lo32, ch 2p+1 hi32), window = 5 rows of 5 bits at
//        6-bit spacing (bit 6r+c). [0..2]=nz-plane pairs, [3..5]=sign pairs.
#define OC1 0
// conv2: per out-ch 6 u64: [0..2]=nz rows (r0|r1<<32, r2|r3<<32, r4),
//        [3..5]=sign. Row = dense 30 bits: ci<3 -> bit 5ci+c, ci>=3 -> 15+5(ci-3)+c.
#define OC2 8      // 16*6 = 96
// fc1: per j (padded to 128): words 0..6 = nz, 7..13 = sign, 14 = pad(0).
//      word k bit (f*16+ch) = wfc1[j][ch*25 + (4k+f)]  (p=4k+f<25)
#define OF1 104    // 128*15 = 1920
// fc2: per j (padded to 128): [0,1]=nz (bits k<120), [2,3]=sign, [4]=pad
#define OF2 2024   // 128*5 = 640
// fc3: per j (10): [0,1]=nz (bits k<84), [2,3]=sign
#define OF3 2664   // 10*4 = 40
#define WTOT 2704  // u64 words = 21632 bytes

__global__ void pack_w(const float* __restrict__ w1, const float* __restrict__ w2,
                       const float* __restrict__ f1, const float* __restrict__ f2,
                       const float* __restrict__ f3, u64* __restrict__ P) {
    int g = blockIdx.x * 256 + threadIdx.x;
    if (g < 1920) {                      // fc1: j*15 + w
        int j = g / 15, w = g % 15;
        u64 v = 0;
        if (w < 14 && j < 120) {
            bool sp = (w >= 7); int k = sp ? w - 7 : w;
            for (int f = 0; f < 4; f++) {
                int p = 4 * k + f;
                if (p < 25)
                    for (int ch = 0; ch < 16; ch++) {
                        float x = f1[j * 400 + ch * 25 + p];
                        bool b = sp ? (x < 0.0f) : (x != 0.0f);
                        if (b) v |= 1ull << (f * 16 + ch);
                    }
            }
        }
        P[OF1 + g] = v;
    } else if (g < 2560) {               // fc2
        int g2 = g - 1920, j = g2 / 5, w = g2 % 5;
        u64 v = 0;
        if (w < 4 && j < 84) {
            bool sp = (w >= 2); int h = w & 1;
            for (int b = 0; b < 64; b++) {
                int k = h * 64 + b;
                if (k < 120) {
                    float x = f2[j * 120 + k];
                    bool bb = sp ? (x < 0.0f) : (x != 0.0f);
                    if (bb) v |= 1ull << b;
                }
            }
        }
        P[OF2 + g2] = v;
    } else if (g < 2600) {               // fc3
        int g3 = g - 2560, j = g3 / 4, w = g3 % 4;
        bool sp = (w >= 2); int h = w & 1;
        u64 v = 0;
        for (int b = 0; b < 64; b++) {
            int k = h * 64 + b;
            if (k < 84) {
                float x = f3[j * 84 + k];
                bool bb = sp ? (x < 0.0f) : (x != 0.0f);
                if (bb) v |= 1ull << b;
            }
        }
        P[OF3 + g3] = v;
    } else if (g < 2696) {               // conv2
        int c = g - 2600, ch = c / 6, w = c % 6;
        bool sp = (w >= 3); int wp = w % 3;
        u64 v = 0;
        for (int half = 0; half < 2; half++) {
            int r = 2 * wp + half;
            if (r < 5) {
                u32 rowv = 0;
                for (int ci = 0; ci < 6; ci++)
                    for (int cc = 0; cc < 5; cc++) {
                        float x = w2[((ch * 6 + ci) * 5 + r) * 5 + cc];
                        bool b = sp ? (x < 0.0f) : (x != 0.0f);
                        int bit = (ci < 3) ? (5 * ci + cc) : (15 + 5 * (ci - 3) + cc);
                        if (b) rowv |= 1u << bit;
                    }
                v |= (u64)rowv << (32 * half);
            }
        }
        P[OC2 + ch * 6 + (sp ? 3 : 0) + wp] = v;
    } else if (g < 2702) {               // conv1
        int c = g - 2696;
        int pair = c % 3; bool sp = (c >= 3);
        u64 v = 0;
        for (int half = 0; half < 2; half++) {
            int ch = 2 * pair + half;
            u32 wd = 0;
            for (int r = 0; r < 5; r++)
                for (int cc = 0; cc < 5; cc++) {
                    float x = w1[ch * 25 + r * 5 + cc];
                    bool b = sp ? (x < 0.0f) : (x != 0.0f);
                    if (b) wd |= 1u << (6 * r + cc);
                }
            v |= (u64)wd << (32 * half);
        }
        P[OC1 + (sp ? 3 : 0) + pair] = v;
    }
}

#define G 4  // images per block

__device__ __forceinline__ u32 sgnb(int v) { return (u32)v >> 31; }
__device__ __forceinline__ u32 nzb(int v)  { return (u32)(v | -v) >> 31; }

__global__ __launch_bounds__(256) void lenet_main(const float* __restrict__ X,
                                                  const u64* __restrict__ P,
                                                  float* __restrict__ out) {
    __shared__ u64 WL[WTOT];
    __shared__ u32 xs[G][32], xn[G][32];
    __shared__ u64 h1An[G][14], h1As[G][14], h1Bn[G][14], h1Bs[G][14];
    __shared__ u64 h2n[G][7], h2s[G][7];
    __shared__ u64 f1s[G][2], f1n[G][2], f2s[G][2], f2n[G][2];

    const int tid = threadIdx.x;
    const int img0 = blockIdx.x * G;

    for (int i = tid; i < WTOT; i += 256) WL[i] = P[i];
    for (int i = tid; i < G * 14; i += 256) {
        int im = i / 14, r = i % 14;
        h1An[im][r] = 0; h1As[im][r] = 0; h1Bn[im][r] = 0; h1Bs[im][r] = 0;
    }
    if (tid < G * 7) { int im = tid / 7, k = tid % 7; h2n[im][k] = 0; h2s[im][k] = 0; }

    // ---- input: load + binarize + ballot-pack rows ----
    const float* Xb = X + (size_t)img0 * 1024;
    for (int it = 0; it < 4 * G; it++) {
        int flat = it * 256 + tid;
        float v = Xb[flat];
        u64 bs = __ballot(v < 0.0f);
        u64 bn = __ballot(v != 0.0f);
        int lane = tid & 63, img = flat >> 10, row = (flat >> 5) & 31;
        if (lane == 0)       { xs[img][row] = (u32)bs;         xn[img][row] = (u32)bn; }
        else if (lane == 32) { xs[img][row] = (u32)(bs >> 32); xn[img][row] = (u32)(bn >> 32); }
    }
    __syncthreads();

    // ---- conv1 + pool: one thread per (img, pooled point), all 6 channels ----
    {
        u64 c1n[3], c1s[3];
        for (int p = 0; p < 3; p++) { c1n[p] = WL[OC1 + p]; c1s[p] = WL[OC1 + 3 + p]; }
        for (int idx = tid; idx < G * 196; idx += 256) {
            int img = idx / 196, rem = idx % 196, py = rem / 14, px = rem % 14;
            int oy = 2 * py;
            u32 rn[6], rs[6];
            for (int k = 0; k < 6; k++) { rn[k] = xn[img][oy + k]; rs[k] = xs[img][oy + k]; }
            int best[6];
            for (int c = 0; c < 6; c++) best[c] = -1000;
            for (int dx = 0; dx < 2; dx++) {
                int t2 = 2 * px + dx;
                u32 srn[6], srs[6];
                for (int k = 0; k < 6; k++) {
                    srn[k] = (rn[k] >> t2) & 31u;
                    srs[k] = (rs[k] >> t2) & 31u;   // MASKED: stray bits would OR into next row's field
                }
                for (int dy = 0; dy < 2; dy++) {
                    u32 wn = 0, ws = 0;
                    for (int r = 0; r < 5; r++) {
                        wn |= srn[dy + r] << (6 * r);
                        ws |= srs[dy + r] << (6 * r);
                    }
                    u64 Wn = ((u64)wn << 32) | wn;
                    u64 Ws = ((u64)ws << 32) | ws;
                    for (int p = 0; p < 3; p++) {
                        u64 m  = Wn & c1n[p];
                        u64 mx = m & (Ws ^ c1s[p]);
                        int a0 = __popc((u32)m) - 2 * __popc((u32)mx);
                        int a1 = __popc((u32)(m >> 32)) - 2 * __popc((u32)(mx >> 32));
                        best[2 * p]     = max(best[2 * p], a0);
                        best[2 * p + 1] = max(best[2 * p + 1], a1);
                    }
                }
            }
            u64 bAs = ((u64)sgnb(best[0]) | ((u64)sgnb(best[1]) << 16) | ((u64)sgnb(best[2]) << 32)) << px;
            u64 bAn = ((u64)nzb(best[0])  | ((u64)nzb(best[1])  << 16) | ((u64)nzb(best[2])  << 32)) << px;
            u64 bBs = ((u64)sgnb(best[3]) | ((u64)sgnb(best[4]) << 16) | ((u64)sgnb(best[5]) << 32)) << px;
            u64 bBn = ((u64)nzb(best[3])  | ((u64)nzb(best[4])  << 16) | ((u64)nzb(best[5])  << 32)) << px;
            atomicOr(&h1As[img][py], bAs);
            atomicOr(&h1An[img][py], bAn);
            atomicOr(&h1Bs[img][py], bBs);
            atomicOr(&h1Bn[img][py], bBn);
        }
    }
    __syncthreads();

    // ---- conv2 + pool: one thread per (img, pooled point), all 16 channels ----
    for (int idx = tid; idx < G * 25; idx += 256) {
        int img = idx / 25, p = idx % 25, py = p / 5, px = p % 5;
        int y0 = 2 * py;
        u64 An[6], As[6], Bn[6], Bs[6];
        for (int k = 0; k < 6; k++) {
            An[k] = h1An[img][y0 + k]; As[k] = h1As[img][y0 + k];
            Bn[k] = h1Bn[img][y0 + k]; Bs[k] = h1Bs[img][y0 + k];
        }
        // build all 4 candidate windows as dense 30-bit rows
        u32 wrn[4][5], wrs[4][5];
        for (int cand = 0; cand < 4; cand++) {
            int dy = cand >> 1, dx = cand & 1, t2 = 2 * px + dx;
            for (int r = 0; r < 5; r++) {
                u64 a_n = An[dy + r] >> t2, a_s = As[dy + r] >> t2;
                u64 b_n = Bn[dy + r] >> t2, b_s = Bs[dy + r] >> t2;
                u32 dAn = ((u32)a_n & 31u) | ((u32)(a_n >> 11) & 0x3E0u) | ((u32)(a_n >> 22) & 0x7C00u);
                u32 dAs = ((u32)a_s & 31u) | ((u32)(a_s >> 11) & 0x3E0u) | ((u32)(a_s >> 22) & 0x7C00u);
                u32 dBn = ((u32)b_n & 31u) | ((u32)(b_n >> 11) & 0x3E0u) | ((u32)(b_n >> 22) & 0x7C00u);
                u32 dBs = ((u32)b_s & 31u) | ((u32)(b_s >> 11) & 0x3E0u) | ((u32)(b_s >> 22) & 0x7C00u);
                wrn[cand][r] = dAn | (dBn << 15);
                wrs[cand][r] = dAs | (dBs << 15);
            }
        }
        u64 sb = 0, nb = 0;
        for (int ch = 0; ch < 16; ch++) {
            const u64* wp = &WL[OC2 + ch * 6];
            u64 w0n = wp[0], w1n = wp[1], w2nv = wp[2];
            u64 w0s = wp[3], w1s = wp[4], w2sv = wp[5];
            int am = -1000000;
            for (int cand = 0; cand < 4; cand++) {
                u64 W0n = ((u64)wrn[cand][1] << 32) | wrn[cand][0];
                u64 W1n = ((u64)wrn[cand][3] << 32) | wrn[cand][2];
                u32 W2n = wrn[cand][4];
                u64 W0s = ((u64)wrs[cand][1] << 32) | wrs[cand][0];
                u64 W1s = ((u64)wrs[cand][3] << 32) | wrs[cand][2];
                u32 W2s = wrs[cand][4];
                u64 m0 = W0n & w0n, m1 = W1n & w1n;
                u32 m2 = W2n & (u32)w2nv;
                u64 x0 = m0 & (W0s ^ w0s), x1 = m1 & (W1s ^ w1s);
                u32 x2 = m2 & (W2s ^ (u32)w2sv);
                int pm = __popcll(m0) + __popcll(m1) + __popc(m2);
                int qm = __popcll(x0) + __popcll(x1) + __popc(x2);
                am = max(am, pm - 2 * qm);
            }
            sb |= (u64)sgnb(am) << ch;
            nb |= (u64)nzb(am) << ch;
        }
        int k = p >> 2, f = p & 3;
        atomicOr(&h2s[img][k], sb << (16 * f));
        atomicOr(&h2n[img][k], nb << (16 * f));
    }
    __syncthreads();

    // ---- fc1: 400 -> 120 (padded 128), ballot packing ----
    for (int r = 0; r < 2; r++) {
        int slot = r * 256 + tid;
        int img = slot >> 7, j = slot & 127, word = (slot >> 6) & 1;
        const u64* wj = &WL[OF1 + j * 15];
        int acc = 0;
        for (int k = 0; k < 7; k++) {
            u64 m  = h2n[img][k] & wj[k];
            u64 mx = m & (h2s[img][k] ^ wj[7 + k]);
            acc += __popcll(m) - 2 * __popcll(mx);
        }
        u64 bs = __ballot(acc < 0);
        u64 bn = __ballot(acc != 0);
        if ((tid & 63) == 0) { f1s[img][word] = bs; f1n[img][word] = bn; }
    }
    __syncthreads();

    // ---- fc2: 120 -> 84 (padded 128), ballot packing ----
    for (int r = 0; r < 2; r++) {
        int slot = r * 256 + tid;
        int img = slot >> 7, j = slot & 127, word = (slot >> 6) & 1;
        const u64* wj = &WL[OF2 + j * 5];
        u64 m0 = f1n[img][0] & wj[0], m1 = f1n[img][1] & wj[1];
        u64 x0 = m0 & (f1s[img][0] ^ wj[2]), x1 = m1 & (f1s[img][1] ^ wj[3]);
        int acc = __popcll(m0) + __popcll(m1) - 2 * (__popcll(x0) + __popcll(x1));
        u64 bs = __ballot(acc < 0);
        u64 bn = __ballot(acc != 0);
        if ((tid & 63) == 0) { f2s[img][word] = bs; f2n[img][word] = bn; }
    }
    __syncthreads();

    // ---- fc3: 84 -> 10, fp32 out ----
    if (tid < 64) {
        int img = tid >> 4, j = tid & 15;
        if (j < 10) {
            const u64* wj = &WL[OF3 + j * 4];
            u64 m0 = f2n[img][0] & wj[0], m1 = f2n[img][1] & wj[1];
            u64 x0 = m0 & (f2s[img][0] ^ wj[2]), x1 = m1 & (f2s[img][1] ^ wj[3]);
            int acc = __popcll(m0) + __popcll(m1) - 2 * (__popcll(x0) + __popcll(x1));
            out[(size_t)(img0 + img) * 10 + j] = (float)acc;
        }
    }
}

extern "C" void kernel_launch(void* const* d_in, const int* in_sizes, int n_in,
                              void* d_out, int out_size, void* d_ws, size_t ws_size,
                              hipStream_t stream) {
    const float* x    = (const float*)d_in[0];
    const float* w1   = (const float*)d_in[1];
    const float* w2   = (const float*)d_in[2];
    const float* wfc1 = (const float*)d_in[3];
    const float* wfc2 = (const float*)d_in[4];
    const float* wfc3 = (const float*)d_in[5];
    float* out = (float*)d_out;
    u64* P = (u64*)d_ws;

    int B = in_sizes[0] / 1024;  // 16384

    pack_w<<<11, 256, 0, stream>>>(w1, w2, wfc1, wfc2, wfc3, P);
    lenet_main<<<B / G, 256, 0, stream>>>(x, P, out);
}

// Round 4
// 187.331 us; speedup vs baseline: 1.9580x; 1.1477x over previous
//
#include <hip/hip_runtime.h>
#include <hip/hip_bf16.h>

typedef unsigned int u32;
typedef unsigned long long u64;

// ---------------- packed-weight layout in d_ws (u64 indices) ----------------
// conv1: 3 ch-pairs (ch 2p lo32, ch 2p+1 hi32), window = 5 rows of 5 bits at
//        6-bit spacing (bit 6r+c). [0..2]=nz-plane pairs, [3..5]=sign pairs.
#define OC1 0
// conv2: per out-ch 6 u64: [0..2]=nz rows (r0|r1<<32, r2|r3<<32, r4),
//        [3..5]=sign. Row = dense 30 bits: ci<3 -> bit 5ci+c, ci>=3 -> 15+5(ci-3)+c.
#define OC2 8      // 16*6 = 96
#define WCONV 104  // u64 words staged in LDS (conv only)
// fc1: per j (padded to 128): words 0..6 = nz, 7..13 = sign, 14 = pad(0).
//      word k bit (f*16+ch) = wfc1[j][ch*25 + (4k+f)]  (p=4k+f<25)
#define OF1 104    // 128*15 = 1920
// fc2: per j (padded to 128): [0,1]=nz (bits k<120), [2,3]=sign, [4]=pad
#define OF2 2024   // 128*5 = 640
// fc3: per j (10): [0,1]=nz (bits k<84), [2,3]=sign
#define OF3 2664   // 10*4 = 40
#define WTOT 2704

__global__ void pack_w(const float* __restrict__ w1, const float* __restrict__ w2,
                       const float* __restrict__ f1, const float* __restrict__ f2,
                       const float* __restrict__ f3, u64* __restrict__ P) {
    int g = blockIdx.x * 256 + threadIdx.x;
    if (g < 1920) {                      // fc1: j*15 + w
        int j = g / 15, w = g % 15;
        u64 v = 0;
        if (w < 14 && j < 120) {
            bool sp = (w >= 7); int k = sp ? w - 7 : w;
            for (int f = 0; f < 4; f++) {
                int p = 4 * k + f;
                if (p < 25)
                    for (int ch = 0; ch < 16; ch++) {
                        float x = f1[j * 400 + ch * 25 + p];
                        bool b = sp ? (x < 0.0f) : (x != 0.0f);
                        if (b) v |= 1ull << (f * 16 + ch);
                    }
            }
        }
        P[OF1 + g] = v;
    } else if (g < 2560) {               // fc2
        int g2 = g - 1920, j = g2 / 5, w = g2 % 5;
        u64 v = 0;
        if (w < 4 && j < 84) {
            bool sp = (w >= 2); int h = w & 1;
            for (int b = 0; b < 64; b++) {
                int k = h * 64 + b;
                if (k < 120) {
                    float x = f2[j * 120 + k];
                    bool bb = sp ? (x < 0.0f) : (x != 0.0f);
                    if (bb) v |= 1ull << b;
                }
            }
        }
        P[OF2 + g2] = v;
    } else if (g < 2600) {               // fc3
        int g3 = g - 2560, j = g3 / 4, w = g3 % 4;
        bool sp = (w >= 2); int h = w & 1;
        u64 v = 0;
        for (int b = 0; b < 64; b++) {
            int k = h * 64 + b;
            if (k < 84) {
                float x = f3[j * 84 + k];
                bool bb = sp ? (x < 0.0f) : (x != 0.0f);
                if (bb) v |= 1ull << b;
            }
        }
        P[OF3 + g3] = v;
    } else if (g < 2696) {               // conv2
        int c = g - 2600, ch = c / 6, w = c % 6;
        bool sp = (w >= 3); int wp = w % 3;
        u64 v = 0;
        for (int half = 0; half < 2; half++) {
            int r = 2 * wp + half;
            if (r < 5) {
                u32 rowv = 0;
                for (int ci = 0; ci < 6; ci++)
                    for (int cc = 0; cc < 5; cc++) {
                        float x = w2[((ch * 6 + ci) * 5 + r) * 5 + cc];
                        bool b = sp ? (x < 0.0f) : (x != 0.0f);
                        int bit = (ci < 3) ? (5 * ci + cc) : (15 + 5 * (ci - 3) + cc);
                        if (b) rowv |= 1u << bit;
                    }
                v |= (u64)rowv << (32 * half);
            }
        }
        P[OC2 + ch * 6 + (sp ? 3 : 0) + wp] = v;
    } else if (g < 2702) {               // conv1
        int c = g - 2696;
        int pair = c % 3; bool sp = (c >= 3);
        u64 v = 0;
        for (int half = 0; half < 2; half++) {
            int ch = 2 * pair + half;
            u32 wd = 0;
            for (int r = 0; r < 5; r++)
                for (int cc = 0; cc < 5; cc++) {
                    float x = w1[ch * 25 + r * 5 + cc];
                    bool b = sp ? (x < 0.0f) : (x != 0.0f);
                    if (b) wd |= 1u << (6 * r + cc);
                }
            v |= (u64)wd << (32 * half);
        }
        P[OC1 + (sp ? 3 : 0) + pair] = v;
    }
}

#define G 4  // images per block

__device__ __forceinline__ u32 sgnb(int v) { return (u32)v >> 31; }
__device__ __forceinline__ u32 nzb(int v)  { return (u32)(v | -v) >> 31; }

__global__ __launch_bounds__(256, 6) void lenet_main(const float* __restrict__ X,
                                                     const u64* __restrict__ P,
                                                     float* __restrict__ out) {
    __shared__ u64 WL[WCONV];                 // conv weights only (832 B)
    __shared__ u32 xs[G][32], xn[G][32];
    __shared__ u64 h1An[G][14], h1As[G][14], h1Bn[G][14], h1Bs[G][14];
    __shared__ u64 h2n[G][7], h2s[G][7];
    __shared__ u64 f1s[G][2], f1n[G][2], f2s[G][2], f2n[G][2];

    const int tid = threadIdx.x;
    const int img0 = blockIdx.x * G;

    if (tid < WCONV) WL[tid] = P[tid];
    for (int i = tid; i < G * 14; i += 256) {
        int im = i / 14, r = i % 14;
        h1An[im][r] = 0; h1As[im][r] = 0; h1Bn[im][r] = 0; h1Bs[im][r] = 0;
    }
    if (tid < G * 7) { int im = tid / 7, k = tid % 7; h2n[im][k] = 0; h2s[im][k] = 0; }

    // ---- input: float4 load + nibble binarize + shfl-xor OR-reduce ----
    {
        const float4* X4 = (const float4*)(X + (size_t)img0 * 1024);
        for (int it = 0; it < G; it++) {          // one image per iteration
            float4 v = X4[it * 256 + tid];
            u32 s = (v.x < 0.0f ? 1u : 0u) | (v.y < 0.0f ? 2u : 0u)
                  | (v.z < 0.0f ? 4u : 0u) | (v.w < 0.0f ? 8u : 0u);
            u32 n = (v.x != 0.0f ? 1u : 0u) | (v.y != 0.0f ? 2u : 0u)
                  | (v.z != 0.0f ? 4u : 0u) | (v.w != 0.0f ? 8u : 0u);
            int pos = 4 * (tid & 7);
            u32 sw = s << pos, nw = n << pos;
            sw |= __shfl_xor((int)sw, 1); sw |= __shfl_xor((int)sw, 2); sw |= __shfl_xor((int)sw, 4);
            nw |= __shfl_xor((int)nw, 1); nw |= __shfl_xor((int)nw, 2); nw |= __shfl_xor((int)nw, 4);
            if ((tid & 7) == 0) { xs[it][tid >> 3] = sw; xn[it][tid >> 3] = nw; }
        }
    }
    __syncthreads();

    // ---- conv1 + pool: one thread per (img, pooled point), all 6 channels ----
    {
        u64 c1n[3], c1s[3];
        for (int p = 0; p < 3; p++) { c1n[p] = WL[OC1 + p]; c1s[p] = WL[OC1 + 3 + p]; }
        for (int idx = tid; idx < G * 196; idx += 256) {
            int img = idx / 196, rem = idx % 196, py = rem / 14, px = rem % 14;
            int oy = 2 * py;
            u32 rn[6], rs[6];
            for (int k = 0; k < 6; k++) { rn[k] = xn[img][oy + k]; rs[k] = xs[img][oy + k]; }
            int best[6];
            for (int c = 0; c < 6; c++) best[c] = -1000;
            for (int dx = 0; dx < 2; dx++) {
                int t2 = 2 * px + dx;
                u32 wn0 = 0, ws0 = 0;
                for (int r = 0; r < 5; r++) {
                    wn0 |= ((rn[r] >> t2) & 31u) << (6 * r);
                    ws0 |= ((rs[r] >> t2) & 31u) << (6 * r);   // masked: no cross-field bleed
                }
                u32 wn1 = (wn0 >> 6) | (((rn[5] >> t2) & 31u) << 24);
                u32 ws1 = (ws0 >> 6) | (((rs[5] >> t2) & 31u) << 24);
                for (int dy = 0; dy < 2; dy++) {
                    u32 wn = dy ? wn1 : wn0, ws = dy ? ws1 : ws0;
                    u64 Wn = ((u64)wn << 32) | wn;
                    u64 Ws = ((u64)ws << 32) | ws;
                    for (int p = 0; p < 3; p++) {
                        u64 m  = Wn & c1n[p];
                        u64 mx = m & (Ws ^ c1s[p]);
                        int a0 = __popc((u32)m) - 2 * __popc((u32)mx);
                        int a1 = __popc((u32)(m >> 32)) - 2 * __popc((u32)(mx >> 32));
                        best[2 * p]     = max(best[2 * p], a0);
                        best[2 * p + 1] = max(best[2 * p + 1], a1);
                    }
                }
            }
            u64 bAs = ((u64)sgnb(best[0]) | ((u64)sgnb(best[1]) << 16) | ((u64)sgnb(best[2]) << 32)) << px;
            u64 bAn = ((u64)nzb(best[0])  | ((u64)nzb(best[1])  << 16) | ((u64)nzb(best[2])  << 32)) << px;
            u64 bBs = ((u64)sgnb(best[3]) | ((u64)sgnb(best[4]) << 16) | ((u64)sgnb(best[5]) << 32)) << px;
            u64 bBn = ((u64)nzb(best[3])  | ((u64)nzb(best[4])  << 16) | ((u64)nzb(best[5])  << 32)) << px;
            atomicOr(&h1As[img][py], bAs);
            atomicOr(&h1An[img][py], bAn);
            atomicOr(&h1Bs[img][py], bBs);
            atomicOr(&h1Bn[img][py], bBn);
        }
    }
    __syncthreads();

    // ---- conv2 + pool: one thread per (img, pooled point), all 16 channels ----
    for (int idx = tid; idx < G * 25; idx += 256) {
        int img = idx / 25, p = idx % 25, py = p / 5, px = p % 5;
        int y0 = 2 * py;
        // 12 dense 30-bit windows: 6 h1 rows x 2 dx (rows read once)
        u32 dn[2][6], dsg[2][6];
        for (int r = 0; r < 6; r++) {
            u64 a_n = h1An[img][y0 + r], a_s = h1As[img][y0 + r];
            u64 b_n = h1Bn[img][y0 + r], b_s = h1Bs[img][y0 + r];
            for (int dx = 0; dx < 2; dx++) {
                int t2 = 2 * px + dx;
                u64 an = a_n >> t2, as = a_s >> t2, bn = b_n >> t2, bs = b_s >> t2;
                dn[dx][r]  = (((u32)an & 31u) | ((u32)(an >> 11) & 0x3E0u) | ((u32)(an >> 22) & 0x7C00u))
                           | ((((u32)bn & 31u) | ((u32)(bn >> 11) & 0x3E0u) | ((u32)(bn >> 22) & 0x7C00u)) << 15);
                dsg[dx][r] = (((u32)as & 31u) | ((u32)(as >> 11) & 0x3E0u) | ((u32)(as >> 22) & 0x7C00u))
                           | ((((u32)bs & 31u) | ((u32)(bs >> 11) & 0x3E0u) | ((u32)(bs >> 22) & 0x7C00u)) << 15);
            }
        }
        // pre-pack row pairs once (shared across all 16 channels)
        u64 Pn[2][4], Ps[2][4];
        for (int dx = 0; dx < 2; dx++)
            for (int r = 0; r < 4; r++) {
                Pn[dx][r] = (u64)dn[dx][r]  | ((u64)dn[dx][r + 1]  << 32);
                Ps[dx][r] = (u64)dsg[dx][r] | ((u64)dsg[dx][r + 1] << 32);
            }
        u64 sb = 0, nb = 0;
        for (int ch = 0; ch < 16; ch++) {
            const u64* wp = &WL[OC2 + ch * 6];
            u64 w0n = wp[0], w1n = wp[1]; u32 w2n = (u32)wp[2];
            u64 w0s = wp[3], w1s = wp[4]; u32 w2s = (u32)wp[5];
            int am = -1000000;
            for (int dy = 0; dy < 2; dy++)
                for (int dx = 0; dx < 2; dx++) {
                    u64 m0 = Pn[dx][dy] & w0n, m1 = Pn[dx][dy + 2] & w1n;
                    u32 m2 = (dy ? dn[dx][5] : dn[dx][4]) & w2n;
                    u64 x0 = m0 & (Ps[dx][dy] ^ w0s), x1 = m1 & (Ps[dx][dy + 2] ^ w1s);
                    u32 x2 = m2 & ((dy ? dsg[dx][5] : dsg[dx][4]) ^ w2s);
                    int v = __popcll(m0) + __popcll(m1) + __popc(m2)
                          - 2 * (__popcll(x0) + __popcll(x1) + __popc(x2));
                    am = max(am, v);
                }
            sb |= (u64)sgnb(am) << ch;
            nb |= (u64)nzb(am) << ch;
        }
        int k = p >> 2, f = p & 3;
        atomicOr(&h2s[img][k], sb << (16 * f));
        atomicOr(&h2n[img][k], nb << (16 * f));
    }
    __syncthreads();

    // ---- fc1: 400 -> 120 (padded 128), weights from global (L2), ballot packing ----
    for (int r = 0; r < 2; r++) {
        int slot = r * 256 + tid;
        int img = slot >> 7, j = slot & 127, word = (slot >> 6) & 1;
        const u64* wj = P + OF1 + j * 15;
        int acc = 0;
        for (int k = 0; k < 7; k++) {
            u64 m  = h2n[img][k] & wj[k];
            u64 mx = m & (h2s[img][k] ^ wj[7 + k]);
            acc += __popcll(m) - 2 * __popcll(mx);
        }
        u64 bs = __ballot(acc < 0);
        u64 bn = __ballot(acc != 0);
        if ((tid & 63) == 0) { f1s[img][word] = bs; f1n[img][word] = bn; }
    }
    __syncthreads();

    // ---- fc2: 120 -> 84 (padded 128), weights from global, ballot packing ----
    for (int r = 0; r < 2; r++) {
        int slot = r * 256 + tid;
        int img = slot >> 7, j = slot & 127, word = (slot >> 6) & 1;
        const u64* wj = P + OF2 + j * 5;
        u64 m0 = f1n[img][0] & wj[0], m1 = f1n[img][1] & wj[1];
        u64 x0 = m0 & (f1s[img][0] ^ wj[2]), x1 = m1 & (f1s[img][1] ^ wj[3]);
        int acc = __popcll(m0) + __popcll(m1) - 2 * (__popcll(x0) + __popcll(x1));
        u64 bs = __ballot(acc < 0);
        u64 bn = __ballot(acc != 0);
        if ((tid & 63) == 0) { f2s[img][word] = bs; f2n[img][word] = bn; }
    }
    __syncthreads();

    // ---- fc3: 84 -> 10, fp32 out ----
    if (tid < 64) {
        int img = tid >> 4, j = tid & 15;
        if (j < 10) {
            const u64* wj = P + OF3 + j * 4;
            u64 m0 = f2n[img][0] & wj[0], m1 = f2n[img][1] & wj[1];
            u64 x0 = m0 & (f2s[img][0] ^ wj[2]), x1 = m1 & (f2s[img][1] ^ wj[3]);
            int acc = __popcll(m0) + __popcll(m1) - 2 * (__popcll(x0) + __popcll(x1));
            out[(size_t)(img0 + img) * 10 + j] = (float)acc;
        }
    }
}

extern "C" void kernel_launch(void* const* d_in, const int* in_sizes, int n_in,
                              void* d_out, int out_size, void* d_ws, size_t ws_size,
                              hipStream_t stream) {
    const float* x    = (const float*)d_in[0];
    const float* w1   = (const float*)d_in[1];
    const float* w2   = (const float*)d_in[2];
    const float* wfc1 = (const float*)d_in[3];
    const float* wfc2 = (const float*)d_in[4];
    const float* wfc3 = (const float*)d_in[5];
    float* out = (float*)d_out;
    u64* P = (u64*)d_ws;

    int B = in_sizes[0] / 1024;  // 16384

    pack_w<<<11, 256, 0, stream>>>(w1, w2, wfc1, wfc2, wfc3, P);
    lenet_main<<<B / G, 256, 0, stream>>>(x, P, out);
}

// Round 5
// 179.990 us; speedup vs baseline: 2.0379x; 1.0408x over previous
//
#include <hip/hip_runtime.h>
#include <hip/hip_bf16.h>

typedef unsigned int u32;
typedef unsigned long long u64;

// ---------------- packed-weight layout in d_ws (u64 indices) ----------------
// conv1: 3 ch-pairs (ch 2p lo32, ch 2p+1 hi32), window = 5 rows of 5 bits at
//        6-bit spacing (bit 6r+c). [0..2]=nz-plane pairs, [3..5]=sign pairs.
#define OC1 0
// conv2: per out-ch 6 u64: [0..2]=nz rows (r0|r1<<32, r2|r3<<32, r4),
//        [3..5]=sign. Row = dense 30 bits: ci<3 -> bit 5ci+c, ci>=3 -> 15+5(ci-3)+c.
#define OC2 8      // 16*6 = 96
#define WCONV 104  // u64 words staged in LDS (conv only)
// fc1: per j (padded to 128): words 0..6 = nz, 7..13 = sign, 14 = pad(0).
#define OF1 104    // 128*15 = 1920
// fc2: per j (padded to 128): [0,1]=nz (bits k<120), [2,3]=sign, [4]=pad
#define OF2 2024   // 128*5 = 640
// fc3: per j (10): [0,1]=nz (bits k<84), [2,3]=sign
#define OF3 2664   // 10*4 = 40
#define WTOT 2704

__global__ void pack_w(const float* __restrict__ w1, const float* __restrict__ w2,
                       const float* __restrict__ f1, const float* __restrict__ f2,
                       const float* __restrict__ f3, u64* __restrict__ P) {
    int g = blockIdx.x * 256 + threadIdx.x;
    if (g < 1920) {                      // fc1: j*15 + w
        int j = g / 15, w = g % 15;
        u64 v = 0;
        if (w < 14 && j < 120) {
            bool sp = (w >= 7); int k = sp ? w - 7 : w;
            for (int f = 0; f < 4; f++) {
                int p = 4 * k + f;
                if (p < 25)
                    for (int ch = 0; ch < 16; ch++) {
                        float x = f1[j * 400 + ch * 25 + p];
                        bool b = sp ? (x < 0.0f) : (x != 0.0f);
                        if (b) v |= 1ull << (f * 16 + ch);
                    }
            }
        }
        P[OF1 + g] = v;
    } else if (g < 2560) {               // fc2
        int g2 = g - 1920, j = g2 / 5, w = g2 % 5;
        u64 v = 0;
        if (w < 4 && j < 84) {
            bool sp = (w >= 2); int h = w & 1;
            for (int b = 0; b < 64; b++) {
                int k = h * 64 + b;
                if (k < 120) {
                    float x = f2[j * 120 + k];
                    bool bb = sp ? (x < 0.0f) : (x != 0.0f);
                    if (bb) v |= 1ull << b;
                }
            }
        }
        P[OF2 + g2] = v;
    } else if (g < 2600) {               // fc3
        int g3 = g - 2560, j = g3 / 4, w = g3 % 4;
        bool sp = (w >= 2); int h = w & 1;
        u64 v = 0;
        for (int b = 0; b < 64; b++) {
            int k = h * 64 + b;
            if (k < 84) {
                float x = f3[j * 84 + k];
                bool bb = sp ? (x < 0.0f) : (x != 0.0f);
                if (bb) v |= 1ull << b;
            }
        }
        P[OF3 + g3] = v;
    } else if (g < 2696) {               // conv2
        int c = g - 2600, ch = c / 6, w = c % 6;
        bool sp = (w >= 3); int wp = w % 3;
        u64 v = 0;
        for (int half = 0; half < 2; half++) {
            int r = 2 * wp + half;
            if (r < 5) {
                u32 rowv = 0;
                for (int ci = 0; ci < 6; ci++)
                    for (int cc = 0; cc < 5; cc++) {
                        float x = w2[((ch * 6 + ci) * 5 + r) * 5 + cc];
                        bool b = sp ? (x < 0.0f) : (x != 0.0f);
                        int bit = (ci < 3) ? (5 * ci + cc) : (15 + 5 * (ci - 3) + cc);
                        if (b) rowv |= 1u << bit;
                    }
                v |= (u64)rowv << (32 * half);
            }
        }
        P[OC2 + ch * 6 + (sp ? 3 : 0) + wp] = v;
    } else if (g < 2702) {               // conv1
        int c = g - 2696;
        int pair = c % 3; bool sp = (c >= 3);
        u64 v = 0;
        for (int half = 0; half < 2; half++) {
            int ch = 2 * pair + half;
            u32 wd = 0;
            for (int r = 0; r < 5; r++)
                for (int cc = 0; cc < 5; cc++) {
                    float x = w1[ch * 25 + r * 5 + cc];
                    bool b = sp ? (x < 0.0f) : (x != 0.0f);
                    if (b) wd |= 1u << (6 * r + cc);
                }
            v |= (u64)wd << (32 * half);
        }
        P[OC1 + (sp ? 3 : 0) + pair] = v;
    }
}

#define G 8  // images per block

__device__ __forceinline__ u32 sgnb(int v) { return (u32)v >> 31; }
__device__ __forceinline__ u32 nzb(int v)  { return (u32)(v | -v) >> 31; }

__global__ __launch_bounds__(256, 8) void lenet_main(const float* __restrict__ X,
                                                     const u64* __restrict__ P,
                                                     float* __restrict__ out) {
    __shared__ u64 WL[WCONV];                 // conv weights only (832 B)
    __shared__ u32 xs[G][32], xn[G][32];
    __shared__ u64 h1An[G][14], h1As[G][14], h1Bn[G][14], h1Bs[G][14];
    __shared__ u64 h2n[G][7], h2s[G][7];
    __shared__ u64 f1s[G][2], f1n[G][2], f2s[G][2], f2n[G][2];

    const int tid = threadIdx.x;
    const int img0 = blockIdx.x * G;

    if (tid < WCONV) WL[tid] = P[tid];
    if (tid < G * 7) { int im = tid / 7, k = tid % 7; h2n[im][k] = 0; h2s[im][k] = 0; }

    // ---- input: float4 load + nibble binarize + shfl-xor OR-reduce ----
    {
        const float4* X4 = (const float4*)(X + (size_t)img0 * 1024);
        for (int it = 0; it < G; it++) {          // one image per iteration
            float4 v = X4[it * 256 + tid];
            u32 s = (v.x < 0.0f ? 1u : 0u) | (v.y < 0.0f ? 2u : 0u)
                  | (v.z < 0.0f ? 4u : 0u) | (v.w < 0.0f ? 8u : 0u);
            u32 n = (v.x != 0.0f ? 1u : 0u) | (v.y != 0.0f ? 2u : 0u)
                  | (v.z != 0.0f ? 4u : 0u) | (v.w != 0.0f ? 8u : 0u);
            int pos = 4 * (tid & 7);
            u32 sw = s << pos, nw = n << pos;
            sw |= __shfl_xor((int)sw, 1); sw |= __shfl_xor((int)sw, 2); sw |= __shfl_xor((int)sw, 4);
            nw |= __shfl_xor((int)nw, 1); nw |= __shfl_xor((int)nw, 2); nw |= __shfl_xor((int)nw, 4);
            if ((tid & 7) == 0) { xs[it][tid >> 3] = sw; xn[it][tid >> 3] = nw; }
        }
    }
    __syncthreads();

    // ---- conv1 + pool: 16-lane segment per (img,row); lane = px; ballot pack,
    //      NO atomics. G*14 = 112 segments = 7 exact passes of 16 segments.
    {
        u64 c1n[3], c1s[3];
        for (int p = 0; p < 3; p++) { c1n[p] = WL[OC1 + p]; c1s[p] = WL[OC1 + 3 + p]; }
        const int px = tid & 15;
        const int pxe = px < 14 ? px : 13;       // lanes 14,15 compute garbage (masked)
        for (int it = 0; it < 7; it++) {
            int seg = it * 16 + (tid >> 4);      // 0..111, always valid
            int img = seg / 14, py = seg % 14;
            int oy = 2 * py;
            u32 rn[6], rs[6];
            for (int k = 0; k < 6; k++) { rn[k] = xn[img][oy + k]; rs[k] = xs[img][oy + k]; }
            int best[6];
            for (int c = 0; c < 6; c++) best[c] = -1000;
            for (int dx = 0; dx < 2; dx++) {
                int t2 = 2 * pxe + dx;
                u32 wn0 = 0, ws0 = 0;
                for (int r = 0; r < 5; r++) {
                    wn0 |= ((rn[r] >> t2) & 31u) << (6 * r);
                    ws0 |= ((rs[r] >> t2) & 31u) << (6 * r);
                }
                u32 wn1 = (wn0 >> 6) | (((rn[5] >> t2) & 31u) << 24);
                u32 ws1 = (ws0 >> 6) | (((rs[5] >> t2) & 31u) << 24);
                for (int dy = 0; dy < 2; dy++) {
                    u32 wn = dy ? wn1 : wn0, ws = dy ? ws1 : ws0;
                    u64 Wn = ((u64)wn << 32) | wn;
                    u64 Ws = ((u64)ws << 32) | ws;
                    for (int p = 0; p < 3; p++) {
                        u64 m  = Wn & c1n[p];
                        u64 mx = m & (Ws ^ c1s[p]);
                        int a0 = __popc((u32)m) - 2 * __popc((u32)mx);
                        int a1 = __popc((u32)(m >> 32)) - 2 * __popc((u32)(mx >> 32));
                        best[2 * p]     = max(best[2 * p], a0);
                        best[2 * p + 1] = max(best[2 * p + 1], a1);
                    }
                }
            }
            u64 bS[6], bN[6];
            for (int c = 0; c < 6; c++) {
                bS[c] = __ballot(best[c] < 0);
                bN[c] = __ballot(best[c] != 0);
            }
            if (px == 0) {
                int sh = tid & 48;               // 16 * segment-within-wave
                u64 rAs = ((bS[0] >> sh) & 0x3FFF) | (((bS[1] >> sh) & 0x3FFF) << 16) | (((bS[2] >> sh) & 0x3FFF) << 32);
                u64 rAn = ((bN[0] >> sh) & 0x3FFF) | (((bN[1] >> sh) & 0x3FFF) << 16) | (((bN[2] >> sh) & 0x3FFF) << 32);
                u64 rBs = ((bS[3] >> sh) & 0x3FFF) | (((bS[4] >> sh) & 0x3FFF) << 16) | (((bS[5] >> sh) & 0x3FFF) << 32);
                u64 rBn = ((bN[3] >> sh) & 0x3FFF) | (((bN[4] >> sh) & 0x3FFF) << 16) | (((bN[5] >> sh) & 0x3FFF) << 32);
                h1As[img][py] = rAs; h1An[img][py] = rAn;
                h1Bs[img][py] = rBs; h1Bn[img][py] = rBn;
            }
        }
    }
    __syncthreads();

    // ---- conv2 + pool: one thread per (img, pooled point), all 16 channels ----
    for (int idx = tid; idx < G * 25; idx += 256) {
        int img = idx / 25, p = idx % 25, py = p / 5, px = p % 5;
        int y0 = 2 * py;
        // 12 dense 30-bit windows: 6 h1 rows x 2 dx (rows read once)
        u32 dn[2][6], dsg[2][6];
        for (int r = 0; r < 6; r++) {
            u64 a_n = h1An[img][y0 + r], a_s = h1As[img][y0 + r];
            u64 b_n = h1Bn[img][y0 + r], b_s = h1Bs[img][y0 + r];
            for (int dx = 0; dx < 2; dx++) {
                int t2 = 2 * px + dx;
                u64 an = a_n >> t2, as = a_s >> t2, bn = b_n >> t2, bs = b_s >> t2;
                dn[dx][r]  = (((u32)an & 31u) | ((u32)(an >> 11) & 0x3E0u) | ((u32)(an >> 22) & 0x7C00u))
                           | ((((u32)bn & 31u) | ((u32)(bn >> 11) & 0x3E0u) | ((u32)(bn >> 22) & 0x7C00u)) << 15);
                dsg[dx][r] = (((u32)as & 31u) | ((u32)(as >> 11) & 0x3E0u) | ((u32)(as >> 22) & 0x7C00u))
                           | ((((u32)bs & 31u) | ((u32)(bs >> 11) & 0x3E0u) | ((u32)(bs >> 22) & 0x7C00u)) << 15);
            }
        }
        // pre-pack row pairs once (shared across all 16 channels)
        u64 Pn[2][4], Ps[2][4];
        for (int dx = 0; dx < 2; dx++)
            for (int r = 0; r < 4; r++) {
                Pn[dx][r] = (u64)dn[dx][r]  | ((u64)dn[dx][r + 1]  << 32);
                Ps[dx][r] = (u64)dsg[dx][r] | ((u64)dsg[dx][r + 1] << 32);
            }
        u64 sb = 0, nb = 0;
        for (int ch = 0; ch < 16; ch++) {
            const u64* wp = &WL[OC2 + ch * 6];
            u64 w0n = wp[0], w1n = wp[1]; u32 w2n = (u32)wp[2];
            u64 w0s = wp[3], w1s = wp[4]; u32 w2s = (u32)wp[5];
            int am = -1000000;
            for (int dy = 0; dy < 2; dy++)
                for (int dx = 0; dx < 2; dx++) {
                    u64 m0 = Pn[dx][dy] & w0n, m1 = Pn[dx][dy + 2] & w1n;
                    u32 m2 = (dy ? dn[dx][5] : dn[dx][4]) & w2n;
                    u64 x0 = m0 & (Ps[dx][dy] ^ w0s), x1 = m1 & (Ps[dx][dy + 2] ^ w1s);
                    u32 x2 = m2 & ((dy ? dsg[dx][5] : dsg[dx][4]) ^ w2s);
                    int v = __popcll(m0) + __popcll(m1) + __popc(m2)
                          - 2 * (__popcll(x0) + __popcll(x1) + __popc(x2));
                    am = max(am, v);
                }
            sb |= (u64)sgnb(am) << ch;
            nb |= (u64)nzb(am) << ch;
        }
        int k = p >> 2, f = p & 3;
        atomicOr(&h2s[img][k], sb << (16 * f));
        atomicOr(&h2n[img][k], nb << (16 * f));
    }
    __syncthreads();

    // ---- fc1: 400 -> 120 (padded 128), weights from global (L2), ballot packing ----
    for (int r = 0; r < G / 2; r++) {
        int slot = r * 256 + tid;
        int img = slot >> 7, j = slot & 127, word = (slot >> 6) & 1;
        const u64* wj = P + OF1 + j * 15;
        int acc = 0;
        for (int k = 0; k < 7; k++) {
            u64 m  = h2n[img][k] & wj[k];
            u64 mx = m & (h2s[img][k] ^ wj[7 + k]);
            acc += __popcll(m) - 2 * __popcll(mx);
        }
        u64 bs = __ballot(acc < 0);
        u64 bn = __ballot(acc != 0);
        if ((tid & 63) == 0) { f1s[img][word] = bs; f1n[img][word] = bn; }
    }
    __syncthreads();

    // ---- fc2: 120 -> 84 (padded 128), weights from global, ballot packing ----
    for (int r = 0; r < G / 2; r++) {
        int slot = r * 256 + tid;
        int img = slot >> 7, j = slot & 127, word = (slot >> 6) & 1;
        const u64* wj = P + OF2 + j * 5;
        u64 m0 = f1n[img][0] & wj[0], m1 = f1n[img][1] & wj[1];
        u64 x0 = m0 & (f1s[img][0] ^ wj[2]), x1 = m1 & (f1s[img][1] ^ wj[3]);
        int acc = __popcll(m0) + __popcll(m1) - 2 * (__popcll(x0) + __popcll(x1));
        u64 bs = __ballot(acc < 0);
        u64 bn = __ballot(acc != 0);
        if ((tid & 63) == 0) { f2s[img][word] = bs; f2n[img][word] = bn; }
    }
    __syncthreads();

    // ---- fc3: 84 -> 10, fp32 out ----
    if (tid < G * 16) {
        int img = tid >> 4, j = tid & 15;
        if (j < 10) {
            const u64* wj = P + OF3 + j * 4;
            u64 m0 = f2n[img][0] & wj[0], m1 = f2n[img][1] & wj[1];
            u64 x0 = m0 & (f2s[img][0] ^ wj[2]), x1 = m1 & (f2s[img][1] ^ wj[3]);
            int acc = __popcll(m0) + __popcll(m1) - 2 * (__popcll(x0) + __popcll(x1));
            out[(size_t)(img0 + img) * 10 + j] = (float)acc;
        }
    }
}

extern "C" void kernel_launch(void* const* d_in, const int* in_sizes, int n_in,
                              void* d_out, int out_size, void* d_ws, size_t ws_size,
                              hipStream_t stream) {
    const float* x    = (const float*)d_in[0];
    const float* w1   = (const float*)d_in[1];
    const float* w2   = (const float*)d_in[2];
    const float* wfc1 = (const float*)d_in[3];
    const float* wfc2 = (const float*)d_in[4];
    const float* wfc3 = (const float*)d_in[5];
    float* out = (float*)d_out;
    u64* P = (u64*)d_ws;

    int B = in_sizes[0] / 1024;  // 16384

    pack_w<<<11, 256, 0, stream>>>(w1, w2, wfc1, wfc2, wfc3, P);
    lenet_main<<<B / G, 256, 0, stream>>>(x, P, out);
}

// Round 6
// 148.267 us; speedup vs baseline: 2.4739x; 1.2140x over previous
//
#include <hip/hip_runtime.h>
#include <hip/hip_bf16.h>

typedef unsigned int u32;
typedef unsigned long long u64;

// ---------------- packed-weight layout in d_ws (u64 indices) ----------------
#define OC1 0      // conv1: 3 nz ch-pair words, then 3 sign ch-pair words
#define OC2 8      // conv2: per out-ch 6 u64: [0..2]=nz rows, [3..5]=sign rows
#define WCONV 104
#define OF1 104    // fc1: per j (pad 128): 0..6 nz, 7..13 sign, 14 pad
#define OF2 2024   // fc2: per j (pad 128): [0,1] nz, [2,3] sign, [4] pad
#define OF3 2664   // fc3: per j: [0,1] nz, [2,3] sign
#define WTOT 2704

__global__ void pack_w(const float* __restrict__ w1, const float* __restrict__ w2,
                       const float* __restrict__ f1, const float* __restrict__ f2,
                       const float* __restrict__ f3, u64* __restrict__ P) {
    int g = blockIdx.x * 256 + threadIdx.x;
    if (g < 1920) {                      // fc1: j*15 + w
        int j = g / 15, w = g % 15;
        u64 v = 0;
        if (w < 14 && j < 120) {
            bool sp = (w >= 7); int k = sp ? w - 7 : w;
            for (int f = 0; f < 4; f++) {
                int p = 4 * k + f;
                if (p < 25)
                    for (int ch = 0; ch < 16; ch++) {
                        float x = f1[j * 400 + ch * 25 + p];
                        bool b = sp ? (x < 0.0f) : (x != 0.0f);
                        if (b) v |= 1ull << (f * 16 + ch);
                    }
            }
        }
        P[OF1 + g] = v;
    } else if (g < 2560) {               // fc2
        int g2 = g - 1920, j = g2 / 5, w = g2 % 5;
        u64 v = 0;
        if (w < 4 && j < 84) {
            bool sp = (w >= 2); int h = w & 1;
            for (int b = 0; b < 64; b++) {
                int k = h * 64 + b;
                if (k < 120) {
                    float x = f2[j * 120 + k];
                    bool bb = sp ? (x < 0.0f) : (x != 0.0f);
                    if (bb) v |= 1ull << b;
                }
            }
        }
        P[OF2 + g2] = v;
    } else if (g < 2600) {               // fc3
        int g3 = g - 2560, j = g3 / 4, w = g3 % 4;
        bool sp = (w >= 2); int h = w & 1;
        u64 v = 0;
        for (int b = 0; b < 64; b++) {
            int k = h * 64 + b;
            if (k < 84) {
                float x = f3[j * 84 + k];
                bool bb = sp ? (x < 0.0f) : (x != 0.0f);
                if (bb) v |= 1ull << b;
            }
        }
        P[OF3 + g3] = v;
    } else if (g < 2696) {               // conv2
        int c = g - 2600, ch = c / 6, w = c % 6;
        bool sp = (w >= 3); int wp = w % 3;
        u64 v = 0;
        for (int half = 0; half < 2; half++) {
            int r = 2 * wp + half;
            if (r < 5) {
                u32 rowv = 0;
                for (int ci = 0; ci < 6; ci++)
                    for (int cc = 0; cc < 5; cc++) {
                        float x = w2[((ch * 6 + ci) * 5 + r) * 5 + cc];
                        bool b = sp ? (x < 0.0f) : (x != 0.0f);
                        int bit = (ci < 3) ? (5 * ci + cc) : (15 + 5 * (ci - 3) + cc);
                        if (b) rowv |= 1u << bit;
                    }
                v |= (u64)rowv << (32 * half);
            }
        }
        P[OC2 + ch * 6 + (sp ? 3 : 0) + wp] = v;
    } else if (g < 2702) {               // conv1
        int c = g - 2696;
        int pair = c % 3; bool sp = (c >= 3);
        u64 v = 0;
        for (int half = 0; half < 2; half++) {
            int ch = 2 * pair + half;
            u32 wd = 0;
            for (int r = 0; r < 5; r++)
                for (int cc = 0; cc < 5; cc++) {
                    float x = w1[ch * 25 + r * 5 + cc];
                    bool b = sp ? (x < 0.0f) : (x != 0.0f);
                    if (b) wd |= 1u << (6 * r + cc);
                }
            v |= (u64)wd << (32 * half);
        }
        P[OC1 + (sp ? 3 : 0) + pair] = v;
    }
}

#define G 8  // images per block

__device__ __forceinline__ u32 sgnb(int v) { return (u32)v >> 31; }
__device__ __forceinline__ u32 nzb(int v)  { return (u32)(v | -v) >> 31; }

__global__ __launch_bounds__(256, 8) void lenet_main(const float* __restrict__ X,
                                                     const u64* __restrict__ P,
                                                     float* __restrict__ out) {
    __shared__ u64 WL[WCONV];
    __shared__ u32 xs[G][32], xn[G][32];
    __shared__ u64 h1An[G][14], h1As[G][14], h1Bn[G][14], h1Bs[G][14];
    __shared__ u64 h2n[G][7], h2s[G][7];
    __shared__ u64 f1s[G][2], f1n[G][2], f2s[G][2], f2n[G][2];
    __shared__ u32 anyz, dirty;

    const int tid = threadIdx.x;
    const int img0 = blockIdx.x * G;

    if (tid < WCONV) WL[tid] = P[tid];
    if (tid < G * 7) { int im = tid / 7, k = tid % 7; h2n[im][k] = 0; h2s[im][k] = 0; }
    if (tid == 0) { anyz = 0; dirty = 0; }
    __syncthreads();

    // weight-cleanliness check: every conv nz-plane word must be full (no exact-0 weights)
    if (tid < 51) {
        u64 w, exp;
        if (tid < 48) {
            int ch = tid / 3, k = tid % 3;
            w = WL[OC2 + ch * 6 + k];
            exp = (k < 2) ? 0x3FFFFFFF3FFFFFFFull : 0x000000003FFFFFFFull;
        } else {
            w = WL[OC1 + (tid - 48)];
            exp = 0x1F7DF7DF1F7DF7DFull;
        }
        if (w != exp) dirty = 1;
    }

    // ---- input: float4 load + nibble binarize + shfl-xor OR-reduce; zero detect ----
    {
        const float4* X4 = (const float4*)(X + (size_t)img0 * 1024);
        for (int it = 0; it < G; it++) {
            float4 v = X4[it * 256 + tid];
            u32 s = (v.x < 0.0f ? 1u : 0u) | (v.y < 0.0f ? 2u : 0u)
                  | (v.z < 0.0f ? 4u : 0u) | (v.w < 0.0f ? 8u : 0u);
            u32 n = (v.x != 0.0f ? 1u : 0u) | (v.y != 0.0f ? 2u : 0u)
                  | (v.z != 0.0f ? 4u : 0u) | (v.w != 0.0f ? 8u : 0u);
            if (n != 15u) anyz = 1;               // some component exactly 0.0
            int pos = 4 * (tid & 7);
            u32 sw = s << pos, nw = n << pos;
            sw |= __shfl_xor((int)sw, 1); sw |= __shfl_xor((int)sw, 2); sw |= __shfl_xor((int)sw, 4);
            nw |= __shfl_xor((int)nw, 1); nw |= __shfl_xor((int)nw, 2); nw |= __shfl_xor((int)nw, 4);
            if ((tid & 7) == 0) { xs[it][tid >> 3] = sw; xn[it][tid >> 3] = nw; }
        }
    }
    __syncthreads();

    const bool fastp = ((anyz | dirty) == 0);

    // ---- conv1 + pool: 16-lane segment per (img,row); lane = px; ballot pack ----
    {
        const int px = tid & 15;
        const int pxe = px < 14 ? px : 13;
        if (fastp) {
            // pure XNOR: val = 25 - 2*popc(S^Ws); max-pool == min popc; h1 never 0
            u64 c1s[3];
            for (int p = 0; p < 3; p++) c1s[p] = WL[OC1 + 3 + p];
            for (int it = 0; it < 7; it++) {
                int seg = it * 16 + (tid >> 4);
                int img = seg / 14, py = seg % 14;
                int oy = 2 * py;
                u32 rs[6];
                for (int k = 0; k < 6; k++) rs[k] = xs[img][oy + k];
                u32 cnt[6];
                for (int c = 0; c < 6; c++) cnt[c] = 255;
                for (int dx = 0; dx < 2; dx++) {
                    int t2 = 2 * pxe + dx;
                    u32 w0 = 0;
                    for (int r = 0; r < 5; r++) w0 |= ((rs[r] >> t2) & 31u) << (6 * r);
                    u32 w1 = (w0 >> 6) | (((rs[5] >> t2) & 31u) << 24);
                    for (int dy = 0; dy < 2; dy++) {
                        u32 w = dy ? w1 : w0;
                        u64 W = ((u64)w << 32) | w;
                        for (int p = 0; p < 3; p++) {
                            u64 t = W ^ c1s[p];
                            cnt[2 * p]     = min(cnt[2 * p],     (u32)__popc((u32)t));
                            cnt[2 * p + 1] = min(cnt[2 * p + 1], (u32)__popc((u32)(t >> 32)));
                        }
                    }
                }
                u64 bS[6];
                for (int c = 0; c < 6; c++) bS[c] = __ballot(cnt[c] >= 13);
                if (px == 0) {
                    int sh = tid & 48;
                    u64 rAs = ((bS[0] >> sh) & 0x3FFF) | (((bS[1] >> sh) & 0x3FFF) << 16) | (((bS[2] >> sh) & 0x3FFF) << 32);
                    u64 rBs = ((bS[3] >> sh) & 0x3FFF) | (((bS[4] >> sh) & 0x3FFF) << 16) | (((bS[5] >> sh) & 0x3FFF) << 32);
                    h1As[img][py] = rAs; h1Bs[img][py] = rBs;
                }
            }
        } else {
            // exact ternary path (round-5)
            u64 c1n[3], c1s[3];
            for (int p = 0; p < 3; p++) { c1n[p] = WL[OC1 + p]; c1s[p] = WL[OC1 + 3 + p]; }
            for (int it = 0; it < 7; it++) {
                int seg = it * 16 + (tid >> 4);
                int img = seg / 14, py = seg % 14;
                int oy = 2 * py;
                u32 rn[6], rs[6];
                for (int k = 0; k < 6; k++) { rn[k] = xn[img][oy + k]; rs[k] = xs[img][oy + k]; }
                int best[6];
                for (int c = 0; c < 6; c++) best[c] = -1000;
                for (int dx = 0; dx < 2; dx++) {
                    int t2 = 2 * pxe + dx;
                    u32 wn0 = 0, ws0 = 0;
                    for (int r = 0; r < 5; r++) {
                        wn0 |= ((rn[r] >> t2) & 31u) << (6 * r);
                        ws0 |= ((rs[r] >> t2) & 31u) << (6 * r);
                    }
                    u32 wn1 = (wn0 >> 6) | (((rn[5] >> t2) & 31u) << 24);
                    u32 ws1 = (ws0 >> 6) | (((rs[5] >> t2) & 31u) << 24);
                    for (int dy = 0; dy < 2; dy++) {
                        u32 wn = dy ? wn1 : wn0, ws = dy ? ws1 : ws0;
                        u64 Wn = ((u64)wn << 32) | wn;
                        u64 Ws = ((u64)ws << 32) | ws;
                        for (int p = 0; p < 3; p++) {
                            u64 m  = Wn & c1n[p];
                            u64 mx = m & (Ws ^ c1s[p]);
                            int a0 = __popc((u32)m) - 2 * __popc((u32)mx);
                            int a1 = __popc((u32)(m >> 32)) - 2 * __popc((u32)(mx >> 32));
                            best[2 * p]     = max(best[2 * p], a0);
                            best[2 * p + 1] = max(best[2 * p + 1], a1);
                        }
                    }
                }
                u64 bS[6], bN[6];
                for (int c = 0; c < 6; c++) {
                    bS[c] = __ballot(best[c] < 0);
                    bN[c] = __ballot(best[c] != 0);
                }
                if (px == 0) {
                    int sh = tid & 48;
                    u64 rAs = ((bS[0] >> sh) & 0x3FFF) | (((bS[1] >> sh) & 0x3FFF) << 16) | (((bS[2] >> sh) & 0x3FFF) << 32);
                    u64 rAn = ((bN[0] >> sh) & 0x3FFF) | (((bN[1] >> sh) & 0x3FFF) << 16) | (((bN[2] >> sh) & 0x3FFF) << 32);
                    u64 rBs = ((bS[3] >> sh) & 0x3FFF) | (((bS[4] >> sh) & 0x3FFF) << 16) | (((bS[5] >> sh) & 0x3FFF) << 32);
                    u64 rBn = ((bN[3] >> sh) & 0x3FFF) | (((bN[4] >> sh) & 0x3FFF) << 16) | (((bN[5] >> sh) & 0x3FFF) << 32);
                    h1As[img][py] = rAs; h1An[img][py] = rAn;
                    h1Bs[img][py] = rBs; h1Bn[img][py] = rBn;
                }
            }
        }
    }
    __syncthreads();

    // ---- conv2 + pool ----
    if (fastp) {
        // h1 in {+-1}: val = 150 - 2*popc(S^Ws); sign: min>=76, nz: min!=75
        for (int idx = tid; idx < G * 25; idx += 256) {
            int img = idx / 25, p = idx % 25, py = p / 5, px = p % 5;
            int y0 = 2 * py;
            u32 dsg[2][6];
            for (int r = 0; r < 6; r++) {
                u64 a = h1As[img][y0 + r], b = h1Bs[img][y0 + r];
                for (int dx = 0; dx < 2; dx++) {
                    int t2 = 2 * px + dx;
                    u64 as = a >> t2, bs = b >> t2;
                    dsg[dx][r] = (((u32)as & 31u) | ((u32)(as >> 11) & 0x3E0u) | ((u32)(as >> 22) & 0x7C00u))
                               | ((((u32)bs & 31u) | ((u32)(bs >> 11) & 0x3E0u) | ((u32)(bs >> 22) & 0x7C00u)) << 15);
                }
            }
            u64 Ps[2][4];
            for (int dx = 0; dx < 2; dx++)
                for (int r = 0; r < 4; r++)
                    Ps[dx][r] = (u64)dsg[dx][r] | ((u64)dsg[dx][r + 1] << 32);
            u64 sb = 0, nb = 0;
            for (int ch = 0; ch < 16; ch++) {
                u64 w0s = WL[OC2 + ch * 6 + 3], w1s = WL[OC2 + ch * 6 + 4];
                u32 w2s = (u32)WL[OC2 + ch * 6 + 5];
                u32 mn = 255;
                for (int dy = 0; dy < 2; dy++)
                    for (int dx = 0; dx < 2; dx++) {
                        u64 t0 = Ps[dx][dy] ^ w0s, t1 = Ps[dx][dy + 2] ^ w1s;
                        u32 t2v = (dy ? dsg[dx][5] : dsg[dx][4]) ^ w2s;
                        u32 c = __popcll(t0) + __popcll(t1) + __popc(t2v);
                        mn = min(mn, c);
                    }
                sb |= (u64)(mn >= 76 ? 1 : 0) << ch;
                nb |= (u64)(mn != 75 ? 1 : 0) << ch;
            }
            int k = p >> 2, f = p & 3;
            atomicOr(&h2s[img][k], sb << (16 * f));
            atomicOr(&h2n[img][k], nb << (16 * f));
        }
    } else {
        for (int idx = tid; idx < G * 25; idx += 256) {
            int img = idx / 25, p = idx % 25, py = p / 5, px = p % 5;
            int y0 = 2 * py;
            u32 dn[2][6], dsg[2][6];
            for (int r = 0; r < 6; r++) {
                u64 a_n = h1An[img][y0 + r], a_s = h1As[img][y0 + r];
                u64 b_n = h1Bn[img][y0 + r], b_s = h1Bs[img][y0 + r];
                for (int dx = 0; dx < 2; dx++) {
                    int t2 = 2 * px + dx;
                    u64 an = a_n >> t2, as = a_s >> t2, bn = b_n >> t2, bs = b_s >> t2;
                    dn[dx][r]  = (((u32)an & 31u) | ((u32)(an >> 11) & 0x3E0u) | ((u32)(an >> 22) & 0x7C00u))
                               | ((((u32)bn & 31u) | ((u32)(bn >> 11) & 0x3E0u) | ((u32)(bn >> 22) & 0x7C00u)) << 15);
                    dsg[dx][r] = (((u32)as & 31u) | ((u32)(as >> 11) & 0x3E0u) | ((u32)(as >> 22) & 0x7C00u))
                               | ((((u32)bs & 31u) | ((u32)(bs >> 11) & 0x3E0u) | ((u32)(bs >> 22) & 0x7C00u)) << 15);
                }
            }
            u64 Pn[2][4], Ps[2][4];
            for (int dx = 0; dx < 2; dx++)
                for (int r = 0; r < 4; r++) {
                    Pn[dx][r] = (u64)dn[dx][r]  | ((u64)dn[dx][r + 1]  << 32);
                    Ps[dx][r] = (u64)dsg[dx][r] | ((u64)dsg[dx][r + 1] << 32);
                }
            u64 sb = 0, nb = 0;
            for (int ch = 0; ch < 16; ch++) {
                const u64* wp = &WL[OC2 + ch * 6];
                u64 w0n = wp[0], w1n = wp[1]; u32 w2n = (u32)wp[2];
                u64 w0s = wp[3], w1s = wp[4]; u32 w2s = (u32)wp[5];
                int am = -1000000;
                for (int dy = 0; dy < 2; dy++)
                    for (int dx = 0; dx < 2; dx++) {
                        u64 m0 = Pn[dx][dy] & w0n, m1 = Pn[dx][dy + 2] & w1n;
                        u32 m2 = (dy ? dn[dx][5] : dn[dx][4]) & w2n;
                        u64 x0 = m0 & (Ps[dx][dy] ^ w0s), x1 = m1 & (Ps[dx][dy + 2] ^ w1s);
                        u32 x2 = m2 & ((dy ? dsg[dx][5] : dsg[dx][4]) ^ w2s);
                        int v = __popcll(m0) + __popcll(m1) + __popc(m2)
                              - 2 * (__popcll(x0) + __popcll(x1) + __popc(x2));
                        am = max(am, v);
                    }
                sb |= (u64)sgnb(am) << ch;
                nb |= (u64)nzb(am) << ch;
            }
            int k = p >> 2, f = p & 3;
            atomicOr(&h2s[img][k], sb << (16 * f));
            atomicOr(&h2n[img][k], nb << (16 * f));
        }
    }
    __syncthreads();

    // ---- fc1: 400 -> 120 (padded 128), weights from global (L2), ballot packing ----
    for (int r = 0; r < G / 2; r++) {
        int slot = r * 256 + tid;
        int img = slot >> 7, j = slot & 127, word = (slot >> 6) & 1;
        const u64* wj = P + OF1 + j * 15;
        int acc = 0;
        for (int k = 0; k < 7; k++) {
            u64 m  = h2n[img][k] & wj[k];
            u64 mx = m & (h2s[img][k] ^ wj[7 + k]);
            acc += __popcll(m) - 2 * __popcll(mx);
        }
        u64 bs = __ballot(acc < 0);
        u64 bn = __ballot(acc != 0);
        if ((tid & 63) == 0) { f1s[img][word] = bs; f1n[img][word] = bn; }
    }
    __syncthreads();

    // ---- fc2: 120 -> 84 (padded 128), weights from global, ballot packing ----
    for (int r = 0; r < G / 2; r++) {
        int slot = r * 256 + tid;
        int img = slot >> 7, j = slot & 127, word = (slot >> 6) & 1;
        const u64* wj = P + OF2 + j * 5;
        u64 m0 = f1n[img][0] & wj[0], m1 = f1n[img][1] & wj[1];
        u64 x0 = m0 & (f1s[img][0] ^ wj[2]), x1 = m1 & (f1s[img][1] ^ wj[3]);
        int acc = __popcll(m0) + __popcll(m1) - 2 * (__popcll(x0) + __popcll(x1));
        u64 bs = __ballot(acc < 0);
        u64 bn = __ballot(acc != 0);
        if ((tid & 63) == 0) { f2s[img][word] = bs; f2n[img][word] = bn; }
    }
    __syncthreads();

    // ---- fc3: 84 -> 10, fp32 out ----
    if (tid < G * 16) {
        int img = tid >> 4, j = tid & 15;
        if (j < 10) {
            const u64* wj = P + OF3 + j * 4;
            u64 m0 = f2n[img][0] & wj[0], m1 = f2n[img][1] & wj[1];
            u64 x0 = m0 & (f2s[img][0] ^ wj[2]), x1 = m1 & (f2s[img][1] ^ wj[3]);
            int acc = __popcll(m0) + __popcll(m1) - 2 * (__popcll(x0) + __popcll(x1));
            out[(size_t)(img0 + img) * 10 + j] = (float)acc;
        }
    }
}

extern "C" void kernel_launch(void* const* d_in, const int* in_sizes, int n_in,
                              void* d_out, int out_size, void* d_ws, size_t ws_size,
                              hipStream_t stream) {
    const float* x    = (const float*)d_in[0];
    const float* w1   = (const float*)d_in[1];
    const float* w2   = (const float*)d_in[2];
    const float* wfc1 = (const float*)d_in[3];
    const float* wfc2 = (const float*)d_in[4];
    const float* wfc3 = (const float*)d_in[5];
    float* out = (float*)d_out;
    u64* P = (u64*)d_ws;

    int B = in_sizes[0] / 1024;  // 16384

    pack_w<<<11, 256, 0, stream>>>(w1, w2, wfc1, wfc2, wfc3, P);
    lenet_main<<<B / G, 256, 0, stream>>>(x, P, out);
}

// Round 7
// 148.213 us; speedup vs baseline: 2.4748x; 1.0004x over previous
//
#include <hip/hip_runtime.h>
#include <hip/hip_bf16.h>

typedef unsigned int u32;
typedef unsigned long long u64;

// ---------------- packed-weight layout in d_ws (u64 indices) ----------------
#define OC1 0      // conv1: 3 nz ch-pair words, then 3 sign ch-pair words
#define OC2 8      // conv2: per out-ch 6 u64: [0..2]=nz rows, [3..5]=sign rows
#define WCONV 104
#define OF1 104    // fc1: per j (pad 128): 0..6 nz, 7..13 sign, 14 pad
#define OF2 2024   // fc2: per j (pad 128): [0,1] nz, [2,3] sign, [4] pad
#define OF3 2664   // fc3: per j: [0,1] nz, [2,3] sign
#define WTOT 2704

__global__ void pack_w(const float* __restrict__ w1, const float* __restrict__ w2,
                       const float* __restrict__ f1, const float* __restrict__ f2,
                       const float* __restrict__ f3, u64* __restrict__ P) {
    int g = blockIdx.x * 256 + threadIdx.x;
    if (g < 1920) {                      // fc1: j*15 + w
        int j = g / 15, w = g % 15;
        u64 v = 0;
        if (w < 14 && j < 120) {
            bool sp = (w >= 7); int k = sp ? w - 7 : w;
            for (int f = 0; f < 4; f++) {
                int p = 4 * k + f;
                if (p < 25)
                    for (int ch = 0; ch < 16; ch++) {
                        float x = f1[j * 400 + ch * 25 + p];
                        bool b = sp ? (x < 0.0f) : (x != 0.0f);
                        if (b) v |= 1ull << (f * 16 + ch);
                    }
            }
        }
        P[OF1 + g] = v;
    } else if (g < 2560) {               // fc2
        int g2 = g - 1920, j = g2 / 5, w = g2 % 5;
        u64 v = 0;
        if (w < 4 && j < 84) {
            bool sp = (w >= 2); int h = w & 1;
            for (int b = 0; b < 64; b++) {
                int k = h * 64 + b;
                if (k < 120) {
                    float x = f2[j * 120 + k];
                    bool bb = sp ? (x < 0.0f) : (x != 0.0f);
                    if (bb) v |= 1ull << b;
                }
            }
        }
        P[OF2 + g2] = v;
    } else if (g < 2600) {               // fc3
        int g3 = g - 2560, j = g3 / 4, w = g3 % 4;
        bool sp = (w >= 2); int h = w & 1;
        u64 v = 0;
        for (int b = 0; b < 64; b++) {
            int k = h * 64 + b;
            if (k < 84) {
                float x = f3[j * 84 + k];
                bool bb = sp ? (x < 0.0f) : (x != 0.0f);
                if (bb) v |= 1ull << b;
            }
        }
        P[OF3 + g3] = v;
    } else if (g < 2696) {               // conv2
        int c = g - 2600, ch = c / 6, w = c % 6;
        bool sp = (w >= 3); int wp = w % 3;
        u64 v = 0;
        for (int half = 0; half < 2; half++) {
            int r = 2 * wp + half;
            if (r < 5) {
                u32 rowv = 0;
                for (int ci = 0; ci < 6; ci++)
                    for (int cc = 0; cc < 5; cc++) {
                        float x = w2[((ch * 6 + ci) * 5 + r) * 5 + cc];
                        bool b = sp ? (x < 0.0f) : (x != 0.0f);
                        int bit = (ci < 3) ? (5 * ci + cc) : (15 + 5 * (ci - 3) + cc);
                        if (b) rowv |= 1u << bit;
                    }
                v |= (u64)rowv << (32 * half);
            }
        }
        P[OC2 + ch * 6 + (sp ? 3 : 0) + wp] = v;
    } else if (g < 2702) {               // conv1
        int c = g - 2696;
        int pair = c % 3; bool sp = (c >= 3);
        u64 v = 0;
        for (int half = 0; half < 2; half++) {
            int ch = 2 * pair + half;
            u32 wd = 0;
            for (int r = 0; r < 5; r++)
                for (int cc = 0; cc < 5; cc++) {
                    float x = w1[ch * 25 + r * 5 + cc];
                    bool b = sp ? (x < 0.0f) : (x != 0.0f);
                    if (b) wd |= 1u << (6 * r + cc);
                }
            v |= (u64)wd << (32 * half);
        }
        P[OC1 + (sp ? 3 : 0) + pair] = v;
    }
}

#define G 8  // images per block (2 per wave, 4 waves)

__device__ __forceinline__ u32 sgnb(int v) { return (u32)v >> 31; }
__device__ __forceinline__ u32 nzb(int v)  { return (u32)(v | -v) >> 31; }
// Within one wave the DS pipe is FIFO, so read-after-write through LDS needs
// only a compiler scheduling fence, not s_barrier:
#define WB() __builtin_amdgcn_wave_barrier()

__global__ __launch_bounds__(256, 8) void lenet_main(const float* __restrict__ X,
                                                     const u64* __restrict__ P,
                                                     float* __restrict__ out) {
    __shared__ u64 WL[WCONV];
    __shared__ u32 xs[G][32], xn[G][32];
    __shared__ u64 h1An[G][14], h1As[G][14], h1Bn[G][14], h1Bs[G][14];
    __shared__ u64 h2n[G][7], h2s[G][7];
    __shared__ u64 f1s[G][2], f1n[G][2], f2s[G][2], f2n[G][2];

    const int tid = threadIdx.x;
    const int wid = tid >> 6, lane = tid & 63;
    const int img0 = blockIdx.x * G;
    const int li0 = wid * 2;          // this wave owns local images li0, li0+1

    if (tid < WCONV) WL[tid] = P[tid];
    __syncthreads();                  // the ONLY block barrier (weight staging)

    // ---- input: float4 load + nibble binarize + shfl-xor pack; per-wave zero detect ----
    u64 zb = 0;
    {
        const float4* X4 = (const float4*)(X + (size_t)img0 * 1024);
        for (int it = 0; it < 8; it++) {
            int li = li0 + (it >> 2);
            int f4 = ((it & 3) << 6) + lane;      // float4 index within image
            float4 v = X4[li * 256 + f4];
            u32 s = (v.x < 0.0f ? 1u : 0u) | (v.y < 0.0f ? 2u : 0u)
                  | (v.z < 0.0f ? 4u : 0u) | (v.w < 0.0f ? 8u : 0u);
            u32 n = (v.x != 0.0f ? 1u : 0u) | (v.y != 0.0f ? 2u : 0u)
                  | (v.z != 0.0f ? 4u : 0u) | (v.w != 0.0f ? 8u : 0u);
            zb |= __ballot(n != 15u);
            int pos = 4 * (f4 & 7);
            u32 sw = s << pos, nw = n << pos;
            sw |= __shfl_xor((int)sw, 1); sw |= __shfl_xor((int)sw, 2); sw |= __shfl_xor((int)sw, 4);
            nw |= __shfl_xor((int)nw, 1); nw |= __shfl_xor((int)nw, 2); nw |= __shfl_xor((int)nw, 4);
            if ((lane & 7) == 0) { xs[li][f4 >> 3] = sw; xn[li][f4 >> 3] = nw; }
        }
    }
    // weight cleanliness (no exact-0 conv weights), wave-uniform via ballot
    u64 db;
    {
        bool bad = false;
        if (lane < 51) {
            u64 w, exp;
            if (lane < 48) {
                int ch = lane / 3, k = lane % 3;
                w = P[OC2 + ch * 6 + k];
                exp = (k < 2) ? 0x3FFFFFFF3FFFFFFFull : 0x000000003FFFFFFFull;
            } else {
                w = P[OC1 + (lane - 48)];
                exp = 0x1F7DF7DF1F7DF7DFull;
            }
            bad = (w != exp);
        }
        db = __ballot(bad);
    }
    const bool fastp = ((zb | db) == 0);
    WB();

    // ---- conv1 + pool: 28 segments (2 img x 14 rows), 4 per pass, 7 passes ----
    {
        const int px = lane & 15;
        const int pxe = px < 14 ? px : 13;
        if (fastp) {
            u64 c1s[3];
            for (int p = 0; p < 3; p++) c1s[p] = WL[OC1 + 3 + p];
            for (int it = 0; it < 7; it++) {
                int seg = it * 4 + (lane >> 4);        // 0..27
                int im = seg >= 14 ? 1 : 0, py = seg - 14 * im, li = li0 + im;
                int oy = 2 * py;
                u32 rs[6];
                for (int k = 0; k < 6; k++) rs[k] = xs[li][oy + k];
                u32 cnt[6];
                for (int c = 0; c < 6; c++) cnt[c] = 255;
                for (int dx = 0; dx < 2; dx++) {
                    int t2 = 2 * pxe + dx;
                    u32 w0 = 0;
                    for (int r = 0; r < 5; r++) w0 |= ((rs[r] >> t2) & 31u) << (6 * r);
                    u32 w1 = (w0 >> 6) | (((rs[5] >> t2) & 31u) << 24);
                    for (int dy = 0; dy < 2; dy++) {
                        u32 w = dy ? w1 : w0;
                        u64 W = ((u64)w << 32) | w;
                        for (int p = 0; p < 3; p++) {
                            u64 t = W ^ c1s[p];
                            cnt[2 * p]     = min(cnt[2 * p],     (u32)__popc((u32)t));
                            cnt[2 * p + 1] = min(cnt[2 * p + 1], (u32)__popc((u32)(t >> 32)));
                        }
                    }
                }
                u64 bS[6];
                for (int c = 0; c < 6; c++) bS[c] = __ballot(cnt[c] >= 13);
                if (px == 0) {
                    int sh = lane & 48;
                    u64 rAs = ((bS[0] >> sh) & 0x3FFF) | (((bS[1] >> sh) & 0x3FFF) << 16) | (((bS[2] >> sh) & 0x3FFF) << 32);
                    u64 rBs = ((bS[3] >> sh) & 0x3FFF) | (((bS[4] >> sh) & 0x3FFF) << 16) | (((bS[5] >> sh) & 0x3FFF) << 32);
                    h1As[li][py] = rAs; h1Bs[li][py] = rBs;
                }
            }
        } else {
            u64 c1n[3], c1s[3];
            for (int p = 0; p < 3; p++) { c1n[p] = WL[OC1 + p]; c1s[p] = WL[OC1 + 3 + p]; }
            for (int it = 0; it < 7; it++) {
                int seg = it * 4 + (lane >> 4);
                int im = seg >= 14 ? 1 : 0, py = seg - 14 * im, li = li0 + im;
                int oy = 2 * py;
                u32 rn[6], rs[6];
                for (int k = 0; k < 6; k++) { rn[k] = xn[li][oy + k]; rs[k] = xs[li][oy + k]; }
                int best[6];
                for (int c = 0; c < 6; c++) best[c] = -1000;
                for (int dx = 0; dx < 2; dx++) {
                    int t2 = 2 * pxe + dx;
                    u32 wn0 = 0, ws0 = 0;
                    for (int r = 0; r < 5; r++) {
                        wn0 |= ((rn[r] >> t2) & 31u) << (6 * r);
                        ws0 |= ((rs[r] >> t2) & 31u) << (6 * r);
                    }
                    u32 wn1 = (wn0 >> 6) | (((rn[5] >> t2) & 31u) << 24);
                    u32 ws1 = (ws0 >> 6) | (((rs[5] >> t2) & 31u) << 24);
                    for (int dy = 0; dy < 2; dy++) {
                        u32 wn = dy ? wn1 : wn0, ws = dy ? ws1 : ws0;
                        u64 Wn = ((u64)wn << 32) | wn;
                        u64 Ws = ((u64)ws << 32) | ws;
                        for (int p = 0; p < 3; p++) {
                            u64 m  = Wn & c1n[p];
                            u64 mx = m & (Ws ^ c1s[p]);
                            int a0 = __popc((u32)m) - 2 * __popc((u32)mx);
                            int a1 = __popc((u32)(m >> 32)) - 2 * __popc((u32)(mx >> 32));
                            best[2 * p]     = max(best[2 * p], a0);
                            best[2 * p + 1] = max(best[2 * p + 1], a1);
                        }
                    }
                }
                u64 bS[6], bN[6];
                for (int c = 0; c < 6; c++) {
                    bS[c] = __ballot(best[c] < 0);
                    bN[c] = __ballot(best[c] != 0);
                }
                if (px == 0) {
                    int sh = lane & 48;
                    u64 rAs = ((bS[0] >> sh) & 0x3FFF) | (((bS[1] >> sh) & 0x3FFF) << 16) | (((bS[2] >> sh) & 0x3FFF) << 32);
                    u64 rAn = ((bN[0] >> sh) & 0x3FFF) | (((bN[1] >> sh) & 0x3FFF) << 16) | (((bN[2] >> sh) & 0x3FFF) << 32);
                    u64 rBs = ((bS[3] >> sh) & 0x3FFF) | (((bS[4] >> sh) & 0x3FFF) << 16) | (((bS[5] >> sh) & 0x3FFF) << 32);
                    u64 rBn = ((bN[3] >> sh) & 0x3FFF) | (((bN[4] >> sh) & 0x3FFF) << 16) | (((bN[5] >> sh) & 0x3FFF) << 32);
                    h1As[li][py] = rAs; h1An[li][py] = rAn;
                    h1Bs[li][py] = rBs; h1Bn[li][py] = rBn;
                }
            }
        }
    }
    WB();

    // ---- conv2 + pool: 50 lanes (2 img x 25 points) ----
    if (lane < 14) { int li = li0 + (lane >= 7 ? 1 : 0); int k = lane % 7; h2n[li][k] = 0; h2s[li][k] = 0; }
    if (fastp) {
        if (lane < 50) {
            int im = lane >= 25 ? 1 : 0, p = lane - 25 * im, li = li0 + im;
            int py = p / 5, px2 = p % 5;
            int y0 = 2 * py;
            u32 dsg[2][6];
            for (int r = 0; r < 6; r++) {
                u64 a = h1As[li][y0 + r], b = h1Bs[li][y0 + r];
                for (int dx = 0; dx < 2; dx++) {
                    int t2 = 2 * px2 + dx;
                    u64 as = a >> t2, bs = b >> t2;
                    dsg[dx][r] = (((u32)as & 31u) | ((u32)(as >> 11) & 0x3E0u) | ((u32)(as >> 22) & 0x7C00u))
                               | ((((u32)bs & 31u) | ((u32)(bs >> 11) & 0x3E0u) | ((u32)(bs >> 22) & 0x7C00u)) << 15);
                }
            }
            u64 Ps[2][4];
            for (int dx = 0; dx < 2; dx++)
                for (int r = 0; r < 4; r++)
                    Ps[dx][r] = (u64)dsg[dx][r] | ((u64)dsg[dx][r + 1] << 32);
            u64 sb = 0, nb = 0;
            for (int ch = 0; ch < 16; ch++) {
                u64 w0s = WL[OC2 + ch * 6 + 3], w1s = WL[OC2 + ch * 6 + 4];
                u32 w2s = (u32)WL[OC2 + ch * 6 + 5];
                u32 mn = 255;
                for (int dy = 0; dy < 2; dy++)
                    for (int dx = 0; dx < 2; dx++) {
                        u64 t0 = Ps[dx][dy] ^ w0s, t1 = Ps[dx][dy + 2] ^ w1s;
                        u32 t2v = (dy ? dsg[dx][5] : dsg[dx][4]) ^ w2s;
                        u32 c = __popcll(t0) + __popcll(t1) + __popc(t2v);
                        mn = min(mn, c);
                    }
                sb |= (u64)(mn >= 76 ? 1 : 0) << ch;
                nb |= (u64)(mn != 75 ? 1 : 0) << ch;
            }
            int k = p >> 2, f = p & 3;
            atomicOr(&h2s[li][k], sb << (16 * f));
            atomicOr(&h2n[li][k], nb << (16 * f));
        }
    } else {
        if (lane < 50) {
            int im = lane >= 25 ? 1 : 0, p = lane - 25 * im, li = li0 + im;
            int py = p / 5, px2 = p % 5;
            int y0 = 2 * py;
            u32 dn[2][6], dsg[2][6];
            for (int r = 0; r < 6; r++) {
                u64 a_n = h1An[li][y0 + r], a_s = h1As[li][y0 + r];
                u64 b_n = h1Bn[li][y0 + r], b_s = h1Bs[li][y0 + r];
                for (int dx = 0; dx < 2; dx++) {
                    int t2 = 2 * px2 + dx;
                    u64 an = a_n >> t2, as = a_s >> t2, bn = b_n >> t2, bs = b_s >> t2;
                    dn[dx][r]  = (((u32)an & 31u) | ((u32)(an >> 11) & 0x3E0u) | ((u32)(an >> 22) & 0x7C00u))
                               | ((((u32)bn & 31u) | ((u32)(bn >> 11) & 0x3E0u) | ((u32)(bn >> 22) & 0x7C00u)) << 15);
                    dsg[dx][r] = (((u32)as & 31u) | ((u32)(as >> 11) & 0x3E0u) | ((u32)(as >> 22) & 0x7C00u))
                               | ((((u32)bs & 31u) | ((u32)(bs >> 11) & 0x3E0u) | ((u32)(bs >> 22) & 0x7C00u)) << 15);
                }
            }
            u64 Pn[2][4], Ps[2][4];
            for (int dx = 0; dx < 2; dx++)
                for (int r = 0; r < 4; r++) {
                    Pn[dx][r] = (u64)dn[dx][r]  | ((u64)dn[dx][r + 1]  << 32);
                    Ps[dx][r] = (u64)dsg[dx][r] | ((u64)dsg[dx][r + 1] << 32);
                }
            u64 sb = 0, nb = 0;
            for (int ch = 0; ch < 16; ch++) {
                const u64* wp = &WL[OC2 + ch * 6];
                u64 w0n = wp[0], w1n = wp[1]; u32 w2n = (u32)wp[2];
                u64 w0s = wp[3], w1s = wp[4]; u32 w2s = (u32)wp[5];
                int am = -1000000;
                for (int dy = 0; dy < 2; dy++)
                    for (int dx = 0; dx < 2; dx++) {
                        u64 m0 = Pn[dx][dy] & w0n, m1 = Pn[dx][dy + 2] & w1n;
                        u32 m2 = (dy ? dn[dx][5] : dn[dx][4]) & w2n;
                        u64 x0 = m0 & (Ps[dx][dy] ^ w0s), x1 = m1 & (Ps[dx][dy + 2] ^ w1s);
                        u32 x2 = m2 & ((dy ? dsg[dx][5] : dsg[dx][4]) ^ w2s);
                        int v = __popcll(m0) + __popcll(m1) + __popc(m2)
                              - 2 * (__popcll(x0) + __popcll(x1) + __popc(x2));
                        am = max(am, v);
                    }
                sb |= (u64)sgnb(am) << ch;
                nb |= (u64)nzb(am) << ch;
            }
            int k = p >> 2, f = p & 3;
            atomicOr(&h2s[li][k], sb << (16 * f));
            atomicOr(&h2n[li][k], nb << (16 * f));
        }
    }
    WB();

    // ---- fc1: 400 -> 120 (pad 128); 4 passes; (im,word) wave-uniform per pass ----
    for (int it = 0; it < 4; it++) {
        int im = it >> 1, word = it & 1, li = li0 + im;
        int j = word * 64 + lane;      // 0..127 across the two passes per image
        const u64* wj = P + OF1 + j * 15;
        int acc = 0;
        for (int k = 0; k < 7; k++) {
            u64 m  = h2n[li][k] & wj[k];
            u64 mx = m & (h2s[li][k] ^ wj[7 + k]);
            acc += __popcll(m) - 2 * __popcll(mx);
        }
        u64 bs = __ballot(acc < 0);
        u64 bn = __ballot(acc != 0);
        if (lane == 0) { f1s[li][word] = bs; f1n[li][word] = bn; }
    }
    WB();

    // ---- fc2: 120 -> 84 (pad 128) ----
    for (int it = 0; it < 4; it++) {
        int im = it >> 1, word = it & 1, li = li0 + im;
        int j = word * 64 + lane;
        const u64* wj = P + OF2 + j * 5;
        u64 m0 = f1n[li][0] & wj[0], m1 = f1n[li][1] & wj[1];
        u64 x0 = m0 & (f1s[li][0] ^ wj[2]), x1 = m1 & (f1s[li][1] ^ wj[3]);
        int acc = __popcll(m0) + __popcll(m1) - 2 * (__popcll(x0) + __popcll(x1));
        u64 bs = __ballot(acc < 0);
        u64 bn = __ballot(acc != 0);
        if (lane == 0) { f2s[li][word] = bs; f2n[li][word] = bn; }
    }
    WB();

    // ---- fc3: 84 -> 10, fp32 out ----
    if (lane < 32) {
        int im = lane >> 4, j = lane & 15, li = li0 + im;
        if (j < 10) {
            const u64* wj = P + OF3 + j * 4;
            u64 m0 = f2n[li][0] & wj[0], m1 = f2n[li][1] & wj[1];
            u64 x0 = m0 & (f2s[li][0] ^ wj[2]), x1 = m1 & (f2s[li][1] ^ wj[3]);
            int acc = __popcll(m0) + __popcll(m1) - 2 * (__popcll(x0) + __popcll(x1));
            out[(size_t)(img0 + li) * 10 + j] = (float)acc;
        }
    }
}

extern "C" void kernel_launch(void* const* d_in, const int* in_sizes, int n_in,
                              void* d_out, int out_size, void* d_ws, size_t ws_size,
                              hipStream_t stream) {
    const float* x    = (const float*)d_in[0];
    const float* w1   = (const float*)d_in[1];
    const float* w2   = (const float*)d_in[2];
    const float* wfc1 = (const float*)d_in[3];
    const float* wfc2 = (const float*)d_in[4];
    const float* wfc3 = (const float*)d_in[5];
    float* out = (float*)d_out;
    u64* P = (u64*)d_ws;

    int B = in_sizes[0] / 1024;  // 16384

    pack_w<<<11, 256, 0, stream>>>(w1, w2, wfc1, wfc2, wfc3, P);
    lenet_main<<<B / G, 256, 0, stream>>>(x, P, out);
}